// Round 6
// baseline (453.251 us; speedup 1.0000x reference)
//
#include <hip/hip_runtime.h>
#include <hip/hip_bf16.h>
#include <stdint.h>

// Problem constants (fixed by setup_inputs)
constexpr int Bn  = 8;
constexpr int Cc  = 512;
constexpr int ICc = 256;
constexpr int HWc = 48 * 48;           // 2304
constexpr float BN_EPS = 1e-5f;

typedef unsigned short u16;
typedef __attribute__((ext_vector_type(8))) short short8;   // 8 bf16 (4 VGPRs)
typedef __attribute__((ext_vector_type(4))) float f32x4;    // 16x16 MFMA C/D
typedef __attribute__((ext_vector_type(16))) float f32x16;  // 32x32 MFMA C/D
typedef __attribute__((ext_vector_type(4))) unsigned int u32x4;

__device__ __forceinline__ u16 f2bf(float f) {
    uint32_t u = __builtin_bit_cast(uint32_t, f);
    u += 0x7fffu + ((u >> 16) & 1u);     // RNE
    return (u16)(u >> 16);
}
__device__ __forceinline__ float bf2f(u16 h) {
    uint32_t u = ((uint32_t)h) << 16;
    return __builtin_bit_cast(float, u);
}
// async global->LDS, 16B per lane; lds dst is wave-uniform base (HW adds lane*16)
__device__ __forceinline__ void load_lds16(const void* g, void* l) {
    __builtin_amdgcn_global_load_lds(
        (const __attribute__((address_space(1))) void*)(uintptr_t)g,
        (__attribute__((address_space(3))) void*)(uintptr_t)l, 16, 0, 0);
}
template <int N> __device__ __forceinline__ void wait_vmcnt() {
    if constexpr (N == 0)      asm volatile("s_waitcnt vmcnt(0)" ::: "memory");
    else if constexpr (N == 3) asm volatile("s_waitcnt vmcnt(3)" ::: "memory");
    else if constexpr (N == 4) asm volatile("s_waitcnt vmcnt(4)" ::: "memory");
    else if constexpr (N == 6) asm volatile("s_waitcnt vmcnt(6)" ::: "memory");
    else if constexpr (N == 8) asm volatile("s_waitcnt vmcnt(8)" ::: "memory");
}
__device__ __forceinline__ void wait_lgkm0() {
    asm volatile("s_waitcnt lgkmcnt(0)" ::: "memory");
}
__device__ __forceinline__ void barrier_fenced() {
    __builtin_amdgcn_s_barrier();
    asm volatile("" ::: "memory");
}

// ---------------------------------------------------------------------------
// Front cast: thph_w bf16 (rows 0..255=th_w, 256..511=ph_w), g_w bf16,
// bias_thph fp32 [th_b | ph_b].
// ---------------------------------------------------------------------------
__global__ __launch_bounds__(256)
void cast_front(const float* __restrict__ th_w, const float* __restrict__ ph_w,
                const float* __restrict__ g_w, const float* __restrict__ th_b,
                const float* __restrict__ ph_b, u16* __restrict__ wcat,
                float* __restrict__ bias_thph) {
    int idx = blockIdx.x * 256 + threadIdx.x;
    if (idx < 98304) {                           // ushort4 casts
        const float4* src;
        if (idx < 32768)       src = (const float4*)th_w + idx;
        else if (idx < 65536)  src = (const float4*)ph_w + (idx - 32768);
        else                   src = (const float4*)g_w  + (idx - 65536);
        float4 v = *src;
        ushort4 o;
        o.x = f2bf(v.x); o.y = f2bf(v.y); o.z = f2bf(v.z); o.w = f2bf(v.w);
        ((ushort4*)wcat)[idx] = o;
    } else if (idx < 98816) {                    // 512 bias floats
        int i = idx - 98304;
        bias_thph[i] = (i < 256) ? th_b[i] : ph_b[i - 256];
    }
}

__global__ __launch_bounds__(256)
void cast_w(const float* __restrict__ a, u16* __restrict__ out) {
    int idx = blockIdx.x * 256 + threadIdx.x;    // 0..32767
    float4 v = ((const float4*)a)[idx];
    ushort4 o;
    o.x = f2bf(v.x); o.y = f2bf(v.y); o.z = f2bf(v.z); o.w = f2bf(v.w);
    ((ushort4*)out)[idx] = o;
}

// ---------------------------------------------------------------------------
// x (B,C,HW) fp32 -> xt (B,HW,C) bf16, 64c x 32p LDS-tiled, ushort2 stores
// ---------------------------------------------------------------------------
__global__ __launch_bounds__(256)
void transpose_cast_x(const float* __restrict__ x, u16* __restrict__ xt) {
    __shared__ float t[64][33];
    const int b = blockIdx.z;
    const int p0 = blockIdx.x * 32;     // HW dir
    const int c0 = blockIdx.y * 64;     // C dir
    const int tx = threadIdx.x & 31, ty = threadIdx.x >> 5;   // ty 0..7
    const float* xb = x + (size_t)b * Cc * HWc;
#pragma unroll
    for (int r = 0; r < 8; ++r)
        t[r * 8 + ty][tx] = xb[(size_t)(c0 + r * 8 + ty) * HWc + p0 + tx];
    __syncthreads();
    u16* xtb = xt + (size_t)b * HWc * Cc;
    const int cc = (threadIdx.x & 31) * 2, pp = threadIdx.x >> 5;
#pragma unroll
    for (int r = 0; r < 4; ++r) {
        int p = r * 8 + pp;
        ushort2 v;
        v.x = f2bf(t[cc][p]);
        v.y = f2bf(t[cc + 1][p]);
        *(ushort2*)&xtb[(size_t)(p0 + p) * Cc + c0 + cc] = v;
    }
}

// ---------------------------------------------------------------------------
// bf16 MFMA GEMM (round-2 verified): C[m][n] = sum_k A[m][k]*B[n][k] (+bias)
// 3-buffer pipeline, counted vmcnt, LDS chunk-XOR swizzle. Used for the
// thph / g / W projections.
// ---------------------------------------------------------------------------
template <int TM, int STORE, bool STATS>
__global__ __launch_bounds__(256, 2)
void mfma_gemm(const u16* __restrict__ A, const u16* __restrict__ B,
               void* __restrict__ Cout, const float* __restrict__ bias,
               int bias_mode, int K, int ldA, int ldB, int ldC,
               size_t sA, size_t sB, size_t sC,
               float* __restrict__ s0g, float* __restrict__ s1g) {
    constexpr int MI  = TM / 32;                 // 4 (TM=128) or 2 (TM=64)
    constexpr int LPS = (TM == 128) ? 4 : 3;     // global_load_lds per wave/stage
    __shared__ __align__(16) u16 As[3][TM * 32];
    __shared__ __align__(16) u16 Bs[3][128 * 32];
    const int bz = blockIdx.z;
    const int m0 = blockIdx.y * TM, n0 = blockIdx.x * 128;
    const u16* Ab = A + (size_t)bz * sA + (size_t)m0 * ldA;
    const u16* Bb = B + (size_t)bz * sB + (size_t)n0 * ldB;
    const int tid = threadIdx.x, lane = tid & 63, w = tid >> 6;
    const int wm = (w & 1) * (TM / 2);
    const int wn = (w >> 1) * 64;
    const int quad = lane >> 4, m16 = lane & 15;

    f32x4 acc[MI][4];
#pragma unroll
    for (int i = 0; i < MI; ++i)
#pragma unroll
        for (int j = 0; j < 4; ++j) acc[i][j] = (f32x4){0.f, 0.f, 0.f, 0.f};

    const int L0 = 2 * w * 64 + lane, L1 = L0 + 64;
    const int br0 = L0 >> 2, bc0 = ((L0 & 3) ^ ((L0 >> 3) & 3)) * 8;
    const int br1 = L1 >> 2, bc1 = ((L1 & 3) ^ ((L1 >> 3) & 3)) * 8;
    const int ar0 = (TM == 128) ? br0 : (tid >> 2);
    const int ac0 = (TM == 128) ? bc0 : (((tid & 3) ^ ((tid >> 3) & 3)) * 8);

    auto stage = [&](int buf, int k0) {
        if (TM == 128) {
            load_lds16(Ab + (size_t)ar0 * ldA + k0 + ac0, &As[buf][2 * w * 512]);
            load_lds16(Ab + (size_t)br1 * ldA + k0 + bc1, &As[buf][(2 * w + 1) * 512]);
        } else {
            load_lds16(Ab + (size_t)ar0 * ldA + k0 + ac0, &As[buf][w * 512]);
        }
        load_lds16(Bb + (size_t)br0 * ldB + k0 + bc0, &Bs[buf][2 * w * 512]);
        load_lds16(Bb + (size_t)br1 * ldB + k0 + bc1, &Bs[buf][(2 * w + 1) * 512]);
    };

    const int sq = (quad ^ ((m16 >> 1) & 3)) * 8;

    auto compute = [&](int buf) {
        short8 af[MI], bfv[4];
#pragma unroll
        for (int i = 0; i < MI; ++i)
            af[i] = *(const short8*)&As[buf][(wm + i * 16 + m16) * 32 + sq];
#pragma unroll
        for (int j = 0; j < 4; ++j)
            bfv[j] = *(const short8*)&Bs[buf][(wn + j * 16 + m16) * 32 + sq];
#pragma unroll
        for (int i = 0; i < MI; ++i)
#pragma unroll
            for (int j = 0; j < 4; ++j)
                acc[i][j] = __builtin_amdgcn_mfma_f32_16x16x32_bf16(
                    af[i], bfv[j], acc[i][j], 0, 0, 0);
    };

    const int nt = K / 32;
    stage(0, 0);
    stage(1, 32);

    int cur = 0;
    for (int t = 0; t < nt - 2; ++t) {
        int nxt = cur + 2; if (nxt >= 3) nxt -= 3;
        stage(nxt, (t + 2) * 32);
        wait_vmcnt<2 * LPS>();
        barrier_fenced();
        compute(cur);
        wait_lgkm0();
        barrier_fenced();
        ++cur; if (cur == 3) cur = 0;
    }
    wait_vmcnt<LPS>();
    barrier_fenced();
    compute(cur);
    wait_lgkm0();
    barrier_fenced();
    ++cur; if (cur == 3) cur = 0;
    wait_vmcnt<0>();
    barrier_fenced();
    compute(cur);

    if (bias_mode) {
#pragma unroll
        for (int i = 0; i < MI; ++i)
#pragma unroll
            for (int j = 0; j < 4; ++j)
#pragma unroll
                for (int r = 0; r < 4; ++r)
                    acc[i][j][r] += (bias_mode == 2)
                        ? bias[m0 + wm + i * 16 + quad * 4 + r]
                        : bias[n0 + wn + j * 16 + m16];
    }

    if (STORE == 0) {
        u16* C = (u16*)Cout + (size_t)bz * sC;
#pragma unroll
        for (int i = 0; i < MI; ++i) {
            int m = m0 + wm + i * 16 + quad * 4;
#pragma unroll
            for (int j = 0; j < 4; ++j) {
                int n = n0 + wn + j * 16 + m16;
#pragma unroll
                for (int r = 0; r < 4; ++r)
                    C[(size_t)(m + r) * ldC + n] = f2bf(acc[i][j][r]);
            }
        }
    } else {
        float* C = (float*)Cout + (size_t)bz * sC;
#pragma unroll
        for (int i = 0; i < MI; ++i) {
            int m = m0 + wm + i * 16 + quad * 4;
#pragma unroll
            for (int j = 0; j < 4; ++j) {
                int n = n0 + wn + j * 16 + m16;
#pragma unroll
                for (int r = 0; r < 4; ++r)
                    C[(size_t)(m + r) * ldC + n] = acc[i][j][r];
            }
        }
    }

    if (STATS) {
#pragma unroll
        for (int i = 0; i < MI; ++i) {
#pragma unroll
            for (int r = 0; r < 4; ++r) {
                float v0 = 0.f, v1 = 0.f;
#pragma unroll
                for (int j = 0; j < 4; ++j) {
                    float v = acc[i][j][r];
                    v0 += v;
                    v1 = fmaf(v, v, v1);
                }
#pragma unroll
                for (int off = 8; off; off >>= 1) {
                    v0 += __shfl_down(v0, off, 16);
                    v1 += __shfl_down(v1, off, 16);
                }
                if (m16 == 0) {
                    int m = m0 + wm + i * 16 + quad * 4 + r;
                    atomicAdd(&s0g[m], v0);
                    atomicAdd(&s1g[m], v1);
                }
            }
        }
    }
}

// ---------------------------------------------------------------------------
// Fused flash attention v4: SWAPPED-operand QK^T and PV (32x32x16 MFMA).
//   thph: (B, HW, 512) bf16, row q = [th(256) | ph(256)]
//   g:    (B, IC=256, HW) bf16 (keys contiguous)  -> y: (B, HW, IC) bf16
//
// v1-v3 post-mortem: MfmaUtil ~11%, ~9k cy/block-iter; the serial cross-lane
// softmax (8 sequential shfl hops x 4 rows x every tile) + P LDS round-trip
// + 2-3 barriers/iter dominated. v4 (guide SB attn structure):
//  - QK swapped: S^T = mfma(A=K, B=Q) -> col q = lane&31 (C/D layout m74/m101:
//    row k = (reg&3)+8*(reg>>2)+4*(lane>>5)). Each lane holds 16 of 32 k for
//    ONE q-row; partner lane^32 holds the rest. Row-reduce = 15 in-lane fmax
//    + ONE shfl_xor(32). m/l/alpha are lane-local scalars.
//  - PV swapped: y^T = mfma(A=V^T, B=P^T) -> col q = lane&31 again, so the
//    online rescale is ONE scalar fmul per acc reg. P^T B-frags assembled
//    in-register: pack exp() results to bf16 pairs, 8 shfl_xor(32) exchange
//    the complementary k-quads (T12 pattern) -> NO P LDS bounce.
//  - ONE barrier per k-tile: stage(t+1) issued first, full compute, vmcnt(0)
//    (stage had the whole iter to land), barrier.
// Block = 128 thr (2 waves = 2 v-halves of 128), q-tile 32, KVBLK 32.
// Grid 576 = 8 batch (id&7 -> XCD L2 pin) x 72 q-tiles; LDS 64KB -> 2 blk/CU.
// K LDS [chunk c 0..31][key r 0..31] and V^T LDS [chunk 0..3][v 0..255]
// interleaved so consecutive lanes read consecutive 16B (minimal conflicts);
// staging sources are the matching per-lane global addresses (linear dst).
// ---------------------------------------------------------------------------
__global__ __launch_bounds__(128, 2)
void fused_attn(const u16* __restrict__ thph, const u16* __restrict__ gmat,
                u16* __restrict__ y) {
    __shared__ __align__(16) u16 Ks[2][8192];   // 16KB/buf: [c][r] 16B units
    __shared__ __align__(16) u16 Vs[2][8192];   // 16KB/buf: [c][v] 16B units
    const int id = blockIdx.x;
    const int b = id & 7, qt = id >> 3;
    const int q0 = qt * 32;
    const u16* tB = thph + (size_t)b * HWc * 512;
    const u16* gB = gmat + (size_t)b * ICc * HWc;
    const int tid = threadIdx.x, lane = tid & 63, w = tid >> 6;  // w = v-half
    const int l31 = lane & 31, h = lane >> 5;

    // ---- Q fragments (B-operand: col q = l31, k=d = ds*16 + h*8 + i)
    short8 qf[16];
#pragma unroll
    for (int ds = 0; ds < 16; ++ds)
        qf[ds] = *(const short8*)&tB[(size_t)(q0 + l31) * 512 + ds * 16 + h * 8];

    // staging: 16 x 1KB loads per wave (8 K + 8 V); linear LDS slots
    auto stage = [&](int buf, int t) {
        const int k0 = t * 32;
#pragma unroll
        for (int u = 0; u < 8; ++u) {
            const int su = w * 8 + u;           // K slot group: c = su*2+h, r=l31
            load_lds16(tB + (size_t)(k0 + l31) * 512 + 256 + (su * 2 + h) * 8,
                       &Ks[buf][su * 512]);
        }
#pragma unroll
        for (int u = 0; u < 8; ++u) {
            const int su = w * 8 + u;           // V slot: c = su>>2, v = (su&3)*64+lane
            load_lds16(gB + (size_t)((su & 3) * 64 + lane) * HWc + k0 + (su >> 2) * 8,
                       &Vs[buf][su * 512]);
        }
    };

    float mrow = -3.0e38f, lrow = 0.f;
    f32x16 acc2[4];
#pragma unroll
    for (int vt = 0; vt < 4; ++vt)
#pragma unroll
        for (int e = 0; e < 16; ++e) acc2[vt][e] = 0.f;

    stage(0, 0);
    wait_vmcnt<0>();                            // drains stage(0) + qf loads
    barrier_fenced();

    constexpr int NT = 72;                      // 2304 / 32
    for (int t = 0; t < NT; ++t) {
        const int buf = t & 1;
        if (t + 1 < NT) stage(buf ^ 1, t + 1);

        // ---- QK^T swapped: acc1 = S^T, col q = l31, row k = crow(e,h)
        f32x16 acc1;
#pragma unroll
        for (int e = 0; e < 16; ++e) acc1[e] = 0.f;
#pragma unroll
        for (int ds = 0; ds < 16; ++ds) {
            short8 kf = *(const short8*)&Ks[buf][((ds * 2 + h) * 32 + l31) * 8];
            acc1 = __builtin_amdgcn_mfma_f32_32x32x16_bf16(kf, qf[ds], acc1, 0, 0, 0);
        }

        // ---- in-lane online softmax for q = l31 (partner lane^32 has the
        //      other 16 k-values; states computed identically in both)
        float tm = acc1[0];
#pragma unroll
        for (int e = 1; e < 16; ++e) tm = fmaxf(tm, acc1[e]);
        tm = fmaxf(tm, __shfl_xor(tm, 32, 64));
        const float mn = fmaxf(mrow, tm);
        const float al = __expf(mrow - mn);
        float rs = 0.f;
#pragma unroll
        for (int e = 0; e < 16; ++e) { acc1[e] = __expf(acc1[e] - mn); rs += acc1[e]; }
        rs += __shfl_xor(rs, 32, 64);
        lrow = lrow * al + rs;
        mrow = mn;

        // ---- pack P to bf16 quads; exchange complementary quads via lane^32
        // own quad g holds k = 8g + 4h + {0..3}
        uint32_t olo[4], ohi[4], slo[4], shi[4];
#pragma unroll
        for (int g = 0; g < 4; ++g) {
            olo[g] = (uint32_t)f2bf(acc1[4 * g + 0]) |
                     ((uint32_t)f2bf(acc1[4 * g + 1]) << 16);
            ohi[g] = (uint32_t)f2bf(acc1[4 * g + 2]) |
                     ((uint32_t)f2bf(acc1[4 * g + 3]) << 16);
            slo[g] = (uint32_t)__shfl_xor((int)olo[g], 32, 64);
            shi[g] = (uint32_t)__shfl_xor((int)ohi[g], 32, 64);
        }

        // ---- rescale y^T accumulator by lane-local alpha (col q = l31)
#pragma unroll
        for (int vt = 0; vt < 4; ++vt)
#pragma unroll
            for (int e = 0; e < 16; ++e) acc2[vt][e] *= al;

        // ---- PV swapped: acc2[vt] += mfma(A = V^T rows w*128+vt*32+l31,
        //                                   B = P^T col q = l31)
#pragma unroll
        for (int ks = 0; ks < 2; ++ks) {
            // B-frag needs k = ks*16 + h*8 + {0..7}:
            //   h=0: quads {own[2ks], sw[2ks]};  h=1: {sw[2ks+1], own[2ks+1]}
            const uint32_t f0 = h ? slo[2 * ks + 1] : olo[2 * ks];
            const uint32_t f1 = h ? shi[2 * ks + 1] : ohi[2 * ks];
            const uint32_t f2 = h ? olo[2 * ks + 1] : slo[2 * ks];
            const uint32_t f3 = h ? ohi[2 * ks + 1] : shi[2 * ks];
            const u32x4 pw = (u32x4){f0, f1, f2, f3};
            const short8 pf = __builtin_bit_cast(short8, pw);
#pragma unroll
            for (int vt = 0; vt < 4; ++vt) {
                short8 vf = *(const short8*)
                    &Vs[buf][((ks * 2 + h) * 256 + w * 128 + vt * 32 + l31) * 8];
                acc2[vt] = __builtin_amdgcn_mfma_f32_32x32x16_bf16(
                    vf, pf, acc2[vt], 0, 0, 0);
            }
        }

        if (t + 1 < NT) {
            wait_vmcnt<0>();                    // stage(t+1) landed (whole iter)
            barrier_fenced();                   // one barrier per k-tile
        }
    }

    // ---- store y[q][v] = acc2 / l  (q = q0+l31; v = w*128+vt*32+8g+4h+j)
    const float linv = 1.0f / lrow;
    u16* yB = y + (size_t)b * HWc * ICc + (size_t)(q0 + l31) * ICc + w * 128;
#pragma unroll
    for (int vt = 0; vt < 4; ++vt)
#pragma unroll
        for (int g = 0; g < 4; ++g) {
            ushort4 o;
            o.x = f2bf(acc2[vt][4 * g + 0] * linv);
            o.y = f2bf(acc2[vt][4 * g + 1] * linv);
            o.z = f2bf(acc2[vt][4 * g + 2] * linv);
            o.w = f2bf(acc2[vt][4 * g + 3] * linv);
            *(ushort4*)&yB[vt * 32 + g * 8 + h * 4] = o;
        }
}

// ---------------------------------------------------------------------------
// Normalize (from raw sums) + affine + residual, float4 vectorized
// ---------------------------------------------------------------------------
__global__ __launch_bounds__(256)
void bn_apply(const float* __restrict__ wy, const float* __restrict__ x,
              const float* __restrict__ s0, const float* __restrict__ s1,
              const float* __restrict__ gamma, const float* __restrict__ beta,
              float* __restrict__ out) {
    const size_t i4 = (size_t)blockIdx.x * 256 + threadIdx.x;
    const size_t base = i4 * 4;
    const int o = (int)((base / HWc) % Cc);
    const float N = (float)(Bn * HWc);
    const float mean = s0[o] / N;
    const float var  = s1[o] / N - mean * mean;
    const float rstd = rsqrtf(var + BN_EPS);
    const float ga = gamma[o];
    const float be = beta[o];
    const float4 w4 = ((const float4*)wy)[i4];
    const float4 x4 = ((const float4*)x)[i4];
    float4 r;
    r.x = (w4.x - mean) * rstd * ga + be + x4.x;
    r.y = (w4.y - mean) * rstd * ga + be + x4.y;
    r.z = (w4.z - mean) * rstd * ga + be + x4.z;
    r.w = (w4.w - mean) * rstd * ga + be + x4.w;
    ((float4*)out)[i4] = r;
}

// ---------------------------------------------------------------------------
extern "C" void kernel_launch(void* const* d_in, const int* in_sizes, int n_in,
                              void* d_out, int out_size, void* d_ws, size_t ws_size,
                              hipStream_t stream) {
    const float* x     = (const float*)d_in[0];
    const float* g_w   = (const float*)d_in[1];
    const float* g_b   = (const float*)d_in[2];
    const float* th_w  = (const float*)d_in[3];
    const float* th_b  = (const float*)d_in[4];
    const float* ph_w  = (const float*)d_in[5];
    const float* ph_b  = (const float*)d_in[6];
    const float* w_w   = (const float*)d_in[7];
    const float* w_b   = (const float*)d_in[8];
    const float* gamma = (const float*)d_in[9];
    const float* beta  = (const float*)d_in[10];

    // Workspace timeline (113.25 MB bound; Sreg = base+28.31M):
    //  base[0,18.87M)    thph bf16 (live through fused)
    //  base[18.87,28.31M) g bf16 (live through fused)
    //  Sreg[0,18.87M)    xt (dead after projections) -> y bf16 [0,9.44M)
    //  Sreg+18.87M       wcat+bias (dead after projections)
    //  Sreg[9.44,47.19M) wy fp32 (post W-gemm)
    //  Sreg+47.19M       wbf2 (262KB); +262144: stats (4KB)
    char* base = (char*)d_ws;
    const size_t SZT = (size_t)Bn * HWc * ICc * 2;        // 9,437,184
    u16* thph = (u16*)base;                               // 18.87 MB
    u16* g    = (u16*)(base + 2 * SZT);                   // 9.44 MB
    char* Sreg = base + 3 * SZT;
    u16* xt   = (u16*)Sreg;                               // 18.87 MB (pre-proj)
    u16* wcat = (u16*)(Sreg + (size_t)Bn * HWc * Cc * 2); // 786 KB (pre-proj)
    float* bias_thph = (float*)(Sreg + (size_t)Bn * HWc * Cc * 2 + 786432);
    u16* y    = (u16*)Sreg;                               // 9.44 MB (post-fused)
    float* wy = (float*)(Sreg + SZT);                     // 37.75 MB
    u16* wbf2 = (u16*)(Sreg + SZT + (size_t)Bn * Cc * HWc * 4);   // 262 KB
    float* stats = (float*)(Sreg + SZT + (size_t)Bn * Cc * HWc * 4 + 262144);

    dim3 blk(256);
    const u16* thphw = wcat;                   // (512,512)
    const u16* gwb   = wcat + 262144;          // (256,512)

    cast_front<<<dim3(386), blk, 0, stream>>>(th_w, ph_w, g_w, th_b, ph_b,
                                              wcat, bias_thph);
    transpose_cast_x<<<dim3(HWc / 32, Cc / 64, Bn), blk, 0, stream>>>(x, xt);

    // thph[q][o] = sum_c xt[q][c]*thph_w[o][c] + bias  (M=2304,N=512,K=512)
    mfma_gemm<128, 0, false><<<dim3(4, 18, Bn), blk, 0, stream>>>(
        xt, thphw, thph, bias_thph, 1, Cc, Cc, Cc, 512,
        (size_t)HWc * Cc, 0, (size_t)HWc * 512, nullptr, nullptr);

    // g[ic][p] = sum_c g_w[ic][c]*xt[p][c] + g_b[ic]   (M=256,N=2304,K=512)
    mfma_gemm<64, 0, false><<<dim3(18, 4, Bn), blk, 0, stream>>>(
        gwb, xt, g, g_b, 2, Cc, Cc, Cc, HWc,
        0, (size_t)HWc * Cc, (size_t)ICc * HWc, nullptr, nullptr);

    // w_w -> bf16 and zero stats (regions never aliased with live data)
    cast_w<<<dim3(128), blk, 0, stream>>>(w_w, wbf2);
    hipMemsetAsync(stats, 0, 2 * Cc * sizeof(float), stream);

    // fused S -> online softmax -> PV  (swapped-operand flash attention)
    fused_attn<<<dim3(576), dim3(128), 0, stream>>>(thph, g, y);

    // wy[o][p] = sum_ic w_w[o][ic]*y[p][ic] + w_b[o]  (M=512,N=2304,K=256)
    mfma_gemm<128, 1, true><<<dim3(18, 4, Bn), blk, 0, stream>>>(
        wbf2, y, wy, w_b, 2, ICc, ICc, ICc, HWc,
        0, (size_t)HWc * ICc, (size_t)Cc * HWc, stats, stats + Cc);

    // BatchNorm apply (stats from raw sums) + affine + residual
    bn_apply<<<dim3((Bn * Cc * HWc) / 4 / 256), blk, 0, stream>>>(
        wy, x, stats, stats + Cc, gamma, beta, (float*)d_out);
}

// Round 7
// 418.170 us; speedup vs baseline: 1.0839x; 1.0839x over previous
//
#include <hip/hip_runtime.h>
#include <hip/hip_bf16.h>
#include <stdint.h>

// Problem constants (fixed by setup_inputs)
constexpr int Bn  = 8;
constexpr int Cc  = 512;
constexpr int ICc = 256;
constexpr int HWc = 48 * 48;           // 2304
constexpr float BN_EPS = 1e-5f;

typedef unsigned short u16;
typedef __attribute__((ext_vector_type(8))) short short8;   // 8 bf16 (4 VGPRs)
typedef __attribute__((ext_vector_type(4))) float f32x4;    // 16x16 MFMA C/D
typedef __attribute__((ext_vector_type(16))) float f32x16;  // 32x32 MFMA C/D
typedef __attribute__((ext_vector_type(4))) unsigned int u32x4;

__device__ __forceinline__ u16 f2bf(float f) {
    uint32_t u = __builtin_bit_cast(uint32_t, f);
    u += 0x7fffu + ((u >> 16) & 1u);     // RNE
    return (u16)(u >> 16);
}
__device__ __forceinline__ float bf2f(u16 h) {
    uint32_t u = ((uint32_t)h) << 16;
    return __builtin_bit_cast(float, u);
}
// async global->LDS, 16B per lane; lds dst is wave-uniform base (HW adds lane*16)
__device__ __forceinline__ void load_lds16(const void* g, void* l) {
    __builtin_amdgcn_global_load_lds(
        (const __attribute__((address_space(1))) void*)(uintptr_t)g,
        (__attribute__((address_space(3))) void*)(uintptr_t)l, 16, 0, 0);
}
template <int N> __device__ __forceinline__ void wait_vmcnt() {
    if constexpr (N == 0)      asm volatile("s_waitcnt vmcnt(0)" ::: "memory");
    else if constexpr (N == 3) asm volatile("s_waitcnt vmcnt(3)" ::: "memory");
    else if constexpr (N == 4) asm volatile("s_waitcnt vmcnt(4)" ::: "memory");
    else if constexpr (N == 6) asm volatile("s_waitcnt vmcnt(6)" ::: "memory");
    else if constexpr (N == 8) asm volatile("s_waitcnt vmcnt(8)" ::: "memory");
}
__device__ __forceinline__ void wait_lgkm0() {
    asm volatile("s_waitcnt lgkmcnt(0)" ::: "memory");
}
__device__ __forceinline__ void barrier_fenced() {
    __builtin_amdgcn_s_barrier();
    asm volatile("" ::: "memory");
}

// ---------------------------------------------------------------------------
// Front cast: thph_w bf16 (rows 0..255=th_w, 256..511=ph_w), g_w bf16,
// bias_thph fp32 [th_b | ph_b].
// ---------------------------------------------------------------------------
__global__ __launch_bounds__(256)
void cast_front(const float* __restrict__ th_w, const float* __restrict__ ph_w,
                const float* __restrict__ g_w, const float* __restrict__ th_b,
                const float* __restrict__ ph_b, u16* __restrict__ wcat,
                float* __restrict__ bias_thph) {
    int idx = blockIdx.x * 256 + threadIdx.x;
    if (idx < 98304) {                           // ushort4 casts
        const float4* src;
        if (idx < 32768)       src = (const float4*)th_w + idx;
        else if (idx < 65536)  src = (const float4*)ph_w + (idx - 32768);
        else                   src = (const float4*)g_w  + (idx - 65536);
        float4 v = *src;
        ushort4 o;
        o.x = f2bf(v.x); o.y = f2bf(v.y); o.z = f2bf(v.z); o.w = f2bf(v.w);
        ((ushort4*)wcat)[idx] = o;
    } else if (idx < 98816) {                    // 512 bias floats
        int i = idx - 98304;
        bias_thph[i] = (i < 256) ? th_b[i] : ph_b[i - 256];
    }
}

__global__ __launch_bounds__(256)
void cast_w(const float* __restrict__ a, u16* __restrict__ out) {
    int idx = blockIdx.x * 256 + threadIdx.x;    // 0..32767
    float4 v = ((const float4*)a)[idx];
    ushort4 o;
    o.x = f2bf(v.x); o.y = f2bf(v.y); o.z = f2bf(v.z); o.w = f2bf(v.w);
    ((ushort4*)out)[idx] = o;
}

// ---------------------------------------------------------------------------
// x (B,C,HW) fp32 -> xt (B,HW,C) bf16, 64c x 32p LDS-tiled, ushort2 stores
// ---------------------------------------------------------------------------
__global__ __launch_bounds__(256)
void transpose_cast_x(const float* __restrict__ x, u16* __restrict__ xt) {
    __shared__ float t[64][33];
    const int b = blockIdx.z;
    const int p0 = blockIdx.x * 32;     // HW dir
    const int c0 = blockIdx.y * 64;     // C dir
    const int tx = threadIdx.x & 31, ty = threadIdx.x >> 5;   // ty 0..7
    const float* xb = x + (size_t)b * Cc * HWc;
#pragma unroll
    for (int r = 0; r < 8; ++r)
        t[r * 8 + ty][tx] = xb[(size_t)(c0 + r * 8 + ty) * HWc + p0 + tx];
    __syncthreads();
    u16* xtb = xt + (size_t)b * HWc * Cc;
    const int cc = (threadIdx.x & 31) * 2, pp = threadIdx.x >> 5;
#pragma unroll
    for (int r = 0; r < 4; ++r) {
        int p = r * 8 + pp;
        ushort2 v;
        v.x = f2bf(t[cc][p]);
        v.y = f2bf(t[cc + 1][p]);
        *(ushort2*)&xtb[(size_t)(p0 + p) * Cc + c0 + cc] = v;
    }
}

// ---------------------------------------------------------------------------
// bf16 MFMA GEMM (round-2 verified): C[m][n] = sum_k A[m][k]*B[n][k] (+bias)
// 3-buffer pipeline, counted vmcnt, LDS chunk-XOR swizzle. Used for the
// thph / g / W projections.
// ---------------------------------------------------------------------------
template <int TM, int STORE, bool STATS>
__global__ __launch_bounds__(256, 2)
void mfma_gemm(const u16* __restrict__ A, const u16* __restrict__ B,
               void* __restrict__ Cout, const float* __restrict__ bias,
               int bias_mode, int K, int ldA, int ldB, int ldC,
               size_t sA, size_t sB, size_t sC,
               float* __restrict__ s0g, float* __restrict__ s1g) {
    constexpr int MI  = TM / 32;                 // 4 (TM=128) or 2 (TM=64)
    constexpr int LPS = (TM == 128) ? 4 : 3;     // global_load_lds per wave/stage
    __shared__ __align__(16) u16 As[3][TM * 32];
    __shared__ __align__(16) u16 Bs[3][128 * 32];
    const int bz = blockIdx.z;
    const int m0 = blockIdx.y * TM, n0 = blockIdx.x * 128;
    const u16* Ab = A + (size_t)bz * sA + (size_t)m0 * ldA;
    const u16* Bb = B + (size_t)bz * sB + (size_t)n0 * ldB;
    const int tid = threadIdx.x, lane = tid & 63, w = tid >> 6;
    const int wm = (w & 1) * (TM / 2);
    const int wn = (w >> 1) * 64;
    const int quad = lane >> 4, m16 = lane & 15;

    f32x4 acc[MI][4];
#pragma unroll
    for (int i = 0; i < MI; ++i)
#pragma unroll
        for (int j = 0; j < 4; ++j) acc[i][j] = (f32x4){0.f, 0.f, 0.f, 0.f};

    const int L0 = 2 * w * 64 + lane, L1 = L0 + 64;
    const int br0 = L0 >> 2, bc0 = ((L0 & 3) ^ ((L0 >> 3) & 3)) * 8;
    const int br1 = L1 >> 2, bc1 = ((L1 & 3) ^ ((L1 >> 3) & 3)) * 8;
    const int ar0 = (TM == 128) ? br0 : (tid >> 2);
    const int ac0 = (TM == 128) ? bc0 : (((tid & 3) ^ ((tid >> 3) & 3)) * 8);

    auto stage = [&](int buf, int k0) {
        if (TM == 128) {
            load_lds16(Ab + (size_t)ar0 * ldA + k0 + ac0, &As[buf][2 * w * 512]);
            load_lds16(Ab + (size_t)br1 * ldA + k0 + bc1, &As[buf][(2 * w + 1) * 512]);
        } else {
            load_lds16(Ab + (size_t)ar0 * ldA + k0 + ac0, &As[buf][w * 512]);
        }
        load_lds16(Bb + (size_t)br0 * ldB + k0 + bc0, &Bs[buf][2 * w * 512]);
        load_lds16(Bb + (size_t)br1 * ldB + k0 + bc1, &Bs[buf][(2 * w + 1) * 512]);
    };

    const int sq = (quad ^ ((m16 >> 1) & 3)) * 8;

    auto compute = [&](int buf) {
        short8 af[MI], bfv[4];
#pragma unroll
        for (int i = 0; i < MI; ++i)
            af[i] = *(const short8*)&As[buf][(wm + i * 16 + m16) * 32 + sq];
#pragma unroll
        for (int j = 0; j < 4; ++j)
            bfv[j] = *(const short8*)&Bs[buf][(wn + j * 16 + m16) * 32 + sq];
#pragma unroll
        for (int i = 0; i < MI; ++i)
#pragma unroll
            for (int j = 0; j < 4; ++j)
                acc[i][j] = __builtin_amdgcn_mfma_f32_16x16x32_bf16(
                    af[i], bfv[j], acc[i][j], 0, 0, 0);
    };

    const int nt = K / 32;
    stage(0, 0);
    stage(1, 32);

    int cur = 0;
    for (int t = 0; t < nt - 2; ++t) {
        int nxt = cur + 2; if (nxt >= 3) nxt -= 3;
        stage(nxt, (t + 2) * 32);
        wait_vmcnt<2 * LPS>();
        barrier_fenced();
        compute(cur);
        wait_lgkm0();
        barrier_fenced();
        ++cur; if (cur == 3) cur = 0;
    }
    wait_vmcnt<LPS>();
    barrier_fenced();
    compute(cur);
    wait_lgkm0();
    barrier_fenced();
    ++cur; if (cur == 3) cur = 0;
    wait_vmcnt<0>();
    barrier_fenced();
    compute(cur);

    if (bias_mode) {
#pragma unroll
        for (int i = 0; i < MI; ++i)
#pragma unroll
            for (int j = 0; j < 4; ++j)
#pragma unroll
                for (int r = 0; r < 4; ++r)
                    acc[i][j][r] += (bias_mode == 2)
                        ? bias[m0 + wm + i * 16 + quad * 4 + r]
                        : bias[n0 + wn + j * 16 + m16];
    }

    if (STORE == 0) {
        u16* C = (u16*)Cout + (size_t)bz * sC;
#pragma unroll
        for (int i = 0; i < MI; ++i) {
            int m = m0 + wm + i * 16 + quad * 4;
#pragma unroll
            for (int j = 0; j < 4; ++j) {
                int n = n0 + wn + j * 16 + m16;
#pragma unroll
                for (int r = 0; r < 4; ++r)
                    C[(size_t)(m + r) * ldC + n] = f2bf(acc[i][j][r]);
            }
        }
    } else {
        float* C = (float*)Cout + (size_t)bz * sC;
#pragma unroll
        for (int i = 0; i < MI; ++i) {
            int m = m0 + wm + i * 16 + quad * 4;
#pragma unroll
            for (int j = 0; j < 4; ++j) {
                int n = n0 + wn + j * 16 + m16;
#pragma unroll
                for (int r = 0; r < 4; ++r)
                    C[(size_t)(m + r) * ldC + n] = acc[i][j][r];
            }
        }
    }

    if (STATS) {
#pragma unroll
        for (int i = 0; i < MI; ++i) {
#pragma unroll
            for (int r = 0; r < 4; ++r) {
                float v0 = 0.f, v1 = 0.f;
#pragma unroll
                for (int j = 0; j < 4; ++j) {
                    float v = acc[i][j][r];
                    v0 += v;
                    v1 = fmaf(v, v, v1);
                }
#pragma unroll
                for (int off = 8; off; off >>= 1) {
                    v0 += __shfl_down(v0, off, 16);
                    v1 += __shfl_down(v1, off, 16);
                }
                if (m16 == 0) {
                    int m = m0 + wm + i * 16 + quad * 4 + r;
                    atomicAdd(&s0g[m], v0);
                    atomicAdd(&s1g[m], v1);
                }
            }
        }
    }
}

// ---------------------------------------------------------------------------
// Fused flash attention v5: v4's swapped-operand structure (softmax fully
// lane-local, one barrier/k-tile) with the two v4 defects fixed:
//  1. COALESCED staging. v4's [chunk][row] LDS layout forced per-lane source
//     rows (stride 1024/4608B) -> every global_load_lds was a 64-cache-line
//     gather (276us, HBM 1%, Occ 7.7%). v5 stores K row-major [r 0..31][256d]
//     with chunk slot c holding source chunk c^(r&7) (read applies same XOR;
//     staging lanes 0-31 read ONE row's 32 chunks permuted within 512B ->
//     fully coalesced). V stored [v 0..255][32k] with c^((v>>1)&3) (64B/row
//     contiguous). Fragment reads: 4-way spread = the 32row x 16B LDS floor.
//  2. OCCUPANCY: 256 threads (4 waves, each owns a 64-v quarter; QK computed
//     redundantly per wave - 16 cheap MFMA). 64KB LDS -> 2 blocks/CU
//     -> 2 waves/SIMD (v4: 1).
// Plus: QK accumulator split into two 8-deep chains (halves dependent-MFMA
// latency); s_setprio(1) around MFMA clusters (T5).
// Grid 576 = 8 batch (id&7 -> XCD L2 pin) x 72 q-tiles of 32.
// ---------------------------------------------------------------------------
__global__ __launch_bounds__(256, 2)
void fused_attn(const u16* __restrict__ thph, const u16* __restrict__ gmat,
                u16* __restrict__ y) {
    __shared__ __align__(16) u16 Ks[2][32 * 256];   // [r][chunk-swz] 16KB/buf
    __shared__ __align__(16) u16 Vs[2][256 * 32];   // [v][chunk-swz] 16KB/buf
    const int id = blockIdx.x;
    const int b = id & 7, qt = id >> 3;
    const int q0 = qt * 32;
    const u16* tB = thph + (size_t)b * HWc * 512;
    const u16* gB = gmat + (size_t)b * ICc * HWc;
    const int tid = threadIdx.x, lane = tid & 63, w = tid >> 6;  // w: v-quarter
    const int l31 = lane & 31, h = lane >> 5;

    // ---- Q fragments (B-operand: col q = l31, k=d = ds*16 + h*8 + {0..7})
    short8 qf[16];
#pragma unroll
    for (int ds = 0; ds < 16; ++ds)
        qf[ds] = *(const short8*)&tB[(size_t)(q0 + l31) * 512 + ds * 16 + h * 8];

    // staging: 8 x 1KB loads per wave (4 K + 4 V), linear LDS dst, coalesced src
    auto stage = [&](int buf, int t) {
        const int k0 = t * 32;
#pragma unroll
        for (int u = 0; u < 4; ++u) {
            const int su = w * 4 + u;
            const int r = su * 2 + h;            // K row this half-wave fills
            load_lds16(tB + (size_t)(k0 + r) * 512 + 256 + ((l31 ^ (r & 7)) * 8),
                       &Ks[buf][su * 512]);
        }
#pragma unroll
        for (int u = 0; u < 4; ++u) {
            const int su = w * 4 + u;
            const int v = su * 16 + (lane >> 2); // V row; 4 lanes per row
            const int c = lane & 3;
            load_lds16(gB + (size_t)v * HWc + k0 + ((c ^ ((lane >> 3) & 3)) * 8),
                       &Vs[buf][su * 512]);
        }
    };

    float mrow = -3.0e38f, lrow = 0.f;
    f32x16 acc2[2];
#pragma unroll
    for (int vt = 0; vt < 2; ++vt)
#pragma unroll
        for (int e = 0; e < 16; ++e) acc2[vt][e] = 0.f;

    stage(0, 0);
    wait_vmcnt<0>();                             // drains stage(0) + qf loads
    barrier_fenced();

    const int kx = l31 & 7;                      // K read XOR (row = l31)
    const int vx = (l31 >> 1) & 3;               // V read XOR
    constexpr int NT = 72;                       // 2304 / 32

    for (int t = 0; t < NT; ++t) {
        const int buf = t & 1;
        if (t + 1 < NT) stage(buf ^ 1, t + 1);

        // ---- QK^T swapped: S^T col q = l31, row k = (e&3)+8*(e>>2)+4*h
        // two independent 8-deep chains
        f32x16 a1a, a1b;
#pragma unroll
        for (int e = 0; e < 16; ++e) { a1a[e] = 0.f; a1b[e] = 0.f; }
        __builtin_amdgcn_s_setprio(1);
#pragma unroll
        for (int ds = 0; ds < 8; ++ds) {
            short8 kf = *(const short8*)
                &Ks[buf][l31 * 256 + (((ds * 2 + h) ^ kx) * 8)];
            a1a = __builtin_amdgcn_mfma_f32_32x32x16_bf16(kf, qf[ds], a1a, 0, 0, 0);
        }
#pragma unroll
        for (int ds = 8; ds < 16; ++ds) {
            short8 kf = *(const short8*)
                &Ks[buf][l31 * 256 + (((ds * 2 + h) ^ kx) * 8)];
            a1b = __builtin_amdgcn_mfma_f32_32x32x16_bf16(kf, qf[ds], a1b, 0, 0, 0);
        }
        __builtin_amdgcn_s_setprio(0);
        f32x16 acc1;
#pragma unroll
        for (int e = 0; e < 16; ++e) acc1[e] = a1a[e] + a1b[e];

        // ---- in-lane online softmax for q = l31 (partner lane^32 holds the
        //      other 16 k; both halves compute identical m/l)
        float tm = acc1[0];
#pragma unroll
        for (int e = 1; e < 16; ++e) tm = fmaxf(tm, acc1[e]);
        tm = fmaxf(tm, __shfl_xor(tm, 32, 64));
        const float mn = fmaxf(mrow, tm);
        const float al = __expf(mrow - mn);
        float rs = 0.f;
#pragma unroll
        for (int e = 0; e < 16; ++e) { acc1[e] = __expf(acc1[e] - mn); rs += acc1[e]; }
        rs += __shfl_xor(rs, 32, 64);
        lrow = lrow * al + rs;
        mrow = mn;

        // ---- pack P to bf16 quads; exchange complementary quads via lane^32
        uint32_t olo[4], ohi[4], slo[4], shi[4];
#pragma unroll
        for (int g = 0; g < 4; ++g) {
            olo[g] = (uint32_t)f2bf(acc1[4 * g + 0]) |
                     ((uint32_t)f2bf(acc1[4 * g + 1]) << 16);
            ohi[g] = (uint32_t)f2bf(acc1[4 * g + 2]) |
                     ((uint32_t)f2bf(acc1[4 * g + 3]) << 16);
            slo[g] = (uint32_t)__shfl_xor((int)olo[g], 32, 64);
            shi[g] = (uint32_t)__shfl_xor((int)ohi[g], 32, 64);
        }

        // ---- rescale y^T accumulator by lane-local alpha (col q = l31)
#pragma unroll
        for (int vt = 0; vt < 2; ++vt)
#pragma unroll
            for (int e = 0; e < 16; ++e) acc2[vt][e] *= al;

        // ---- PV swapped: acc2[vt] += mfma(A = V rows w*64+vt*32+l31, B = P^T)
        __builtin_amdgcn_s_setprio(1);
#pragma unroll
        for (int ks = 0; ks < 2; ++ks) {
            // B-frag k = ks*16 + h*8 + {0..7}:
            //   h=0: quads {own[2ks], sw[2ks]};  h=1: {sw[2ks+1], own[2ks+1]}
            const uint32_t f0 = h ? slo[2 * ks + 1] : olo[2 * ks];
            const uint32_t f1 = h ? shi[2 * ks + 1] : ohi[2 * ks];
            const uint32_t f2 = h ? olo[2 * ks + 1] : slo[2 * ks];
            const uint32_t f3 = h ? ohi[2 * ks + 1] : shi[2 * ks];
            const u32x4 pw = (u32x4){f0, f1, f2, f3};
            const short8 pf = __builtin_bit_cast(short8, pw);
#pragma unroll
            for (int vt = 0; vt < 2; ++vt) {
                const int v = w * 64 + vt * 32 + l31;
                short8 vf = *(const short8*)
                    &Vs[buf][v * 32 + (((ks * 2 + h) ^ vx) * 8)];
                acc2[vt] = __builtin_amdgcn_mfma_f32_32x32x16_bf16(
                    vf, pf, acc2[vt], 0, 0, 0);
            }
        }
        __builtin_amdgcn_s_setprio(0);

        if (t + 1 < NT) {
            wait_vmcnt<0>();                     // stage(t+1) landed (whole iter)
            barrier_fenced();                    // one barrier per k-tile
        }
    }

    // ---- store y[q][v] = acc2 / l  (q = q0+l31; v = w*64+vt*32+8g+4h+{0..3})
    const float linv = 1.0f / lrow;
    u16* yB = y + (size_t)b * HWc * ICc + (size_t)(q0 + l31) * ICc + w * 64;
#pragma unroll
    for (int vt = 0; vt < 2; ++vt)
#pragma unroll
        for (int g = 0; g < 4; ++g) {
            ushort4 o;
            o.x = f2bf(acc2[vt][4 * g + 0] * linv);
            o.y = f2bf(acc2[vt][4 * g + 1] * linv);
            o.z = f2bf(acc2[vt][4 * g + 2] * linv);
            o.w = f2bf(acc2[vt][4 * g + 3] * linv);
            *(ushort4*)&yB[vt * 32 + g * 8 + h * 4] = o;
        }
}

// ---------------------------------------------------------------------------
// Normalize (from raw sums) + affine + residual, float4 vectorized
// ---------------------------------------------------------------------------
__global__ __launch_bounds__(256)
void bn_apply(const float* __restrict__ wy, const float* __restrict__ x,
              const float* __restrict__ s0, const float* __restrict__ s1,
              const float* __restrict__ gamma, const float* __restrict__ beta,
              float* __restrict__ out) {
    const size_t i4 = (size_t)blockIdx.x * 256 + threadIdx.x;
    const size_t base = i4 * 4;
    const int o = (int)((base / HWc) % Cc);
    const float N = (float)(Bn * HWc);
    const float mean = s0[o] / N;
    const float var  = s1[o] / N - mean * mean;
    const float rstd = rsqrtf(var + BN_EPS);
    const float ga = gamma[o];
    const float be = beta[o];
    const float4 w4 = ((const float4*)wy)[i4];
    const float4 x4 = ((const float4*)x)[i4];
    float4 r;
    r.x = (w4.x - mean) * rstd * ga + be + x4.x;
    r.y = (w4.y - mean) * rstd * ga + be + x4.y;
    r.z = (w4.z - mean) * rstd * ga + be + x4.z;
    r.w = (w4.w - mean) * rstd * ga + be + x4.w;
    ((float4*)out)[i4] = r;
}

// ---------------------------------------------------------------------------
extern "C" void kernel_launch(void* const* d_in, const int* in_sizes, int n_in,
                              void* d_out, int out_size, void* d_ws, size_t ws_size,
                              hipStream_t stream) {
    const float* x     = (const float*)d_in[0];
    const float* g_w   = (const float*)d_in[1];
    const float* g_b   = (const float*)d_in[2];
    const float* th_w  = (const float*)d_in[3];
    const float* th_b  = (const float*)d_in[4];
    const float* ph_w  = (const float*)d_in[5];
    const float* ph_b  = (const float*)d_in[6];
    const float* w_w   = (const float*)d_in[7];
    const float* w_b   = (const float*)d_in[8];
    const float* gamma = (const float*)d_in[9];
    const float* beta  = (const float*)d_in[10];

    // Workspace timeline (113.25 MB bound; Sreg = base+28.31M):
    //  base[0,18.87M)    thph bf16 (live through fused)
    //  base[18.87,28.31M) g bf16 (live through fused)
    //  Sreg[0,18.87M)    xt (dead after projections) -> y bf16 [0,9.44M)
    //  Sreg+18.87M       wcat+bias (dead after projections)
    //  Sreg[9.44,47.19M) wy fp32 (post W-gemm)
    //  Sreg+47.19M       wbf2 (262KB); +262144: stats (4KB)
    char* base = (char*)d_ws;
    const size_t SZT = (size_t)Bn * HWc * ICc * 2;        // 9,437,184
    u16* thph = (u16*)base;                               // 18.87 MB
    u16* g    = (u16*)(base + 2 * SZT);                   // 9.44 MB
    char* Sreg = base + 3 * SZT;
    u16* xt   = (u16*)Sreg;                               // 18.87 MB (pre-proj)
    u16* wcat = (u16*)(Sreg + (size_t)Bn * HWc * Cc * 2); // 786 KB (pre-proj)
    float* bias_thph = (float*)(Sreg + (size_t)Bn * HWc * Cc * 2 + 786432);
    u16* y    = (u16*)Sreg;                               // 9.44 MB (post-fused)
    float* wy = (float*)(Sreg + SZT);                     // 37.75 MB
    u16* wbf2 = (u16*)(Sreg + SZT + (size_t)Bn * Cc * HWc * 4);   // 262 KB
    float* stats = (float*)(Sreg + SZT + (size_t)Bn * Cc * HWc * 4 + 262144);

    dim3 blk(256);
    const u16* thphw = wcat;                   // (512,512)
    const u16* gwb   = wcat + 262144;          // (256,512)

    cast_front<<<dim3(386), blk, 0, stream>>>(th_w, ph_w, g_w, th_b, ph_b,
                                              wcat, bias_thph);
    transpose_cast_x<<<dim3(HWc / 32, Cc / 64, Bn), blk, 0, stream>>>(x, xt);

    // thph[q][o] = sum_c xt[q][c]*thph_w[o][c] + bias  (M=2304,N=512,K=512)
    mfma_gemm<128, 0, false><<<dim3(4, 18, Bn), blk, 0, stream>>>(
        xt, thphw, thph, bias_thph, 1, Cc, Cc, Cc, 512,
        (size_t)HWc * Cc, 0, (size_t)HWc * 512, nullptr, nullptr);

    // g[ic][p] = sum_c g_w[ic][c]*xt[p][c] + g_b[ic]   (M=256,N=2304,K=512)
    mfma_gemm<64, 0, false><<<dim3(18, 4, Bn), blk, 0, stream>>>(
        gwb, xt, g, g_b, 2, Cc, Cc, Cc, HWc,
        0, (size_t)HWc * Cc, (size_t)ICc * HWc, nullptr, nullptr);

    // w_w -> bf16 and zero stats (regions never aliased with live data)
    cast_w<<<dim3(128), blk, 0, stream>>>(w_w, wbf2);
    hipMemsetAsync(stats, 0, 2 * Cc * sizeof(float), stream);

    // fused S -> online softmax -> PV  (swapped-operand flash attention)
    fused_attn<<<dim3(576), blk, 0, stream>>>(thph, g, y);

    // wy[o][p] = sum_ic w_w[o][ic]*y[p][ic] + w_b[o]  (M=512,N=2304,K=256)
    mfma_gemm<128, 1, true><<<dim3(18, 4, Bn), blk, 0, stream>>>(
        wbf2, y, wy, w_b, 2, ICc, ICc, ICc, HWc,
        0, (size_t)HWc * ICc, (size_t)Cc * HWc, stats, stats + Cc);

    // BatchNorm apply (stats from raw sums) + affine + residual
    bn_apply<<<dim3((Bn * Cc * HWc) / 4 / 256), blk, 0, stream>>>(
        wy, x, stats, stats + Cc, gamma, beta, (float*)d_out);
}

// Round 8
// 322.565 us; speedup vs baseline: 1.4051x; 1.2964x over previous
//
#include <hip/hip_runtime.h>
#include <hip/hip_bf16.h>
#include <stdint.h>

// Problem constants (fixed by setup_inputs)
constexpr int Bn  = 8;
constexpr int Cc  = 512;
constexpr int ICc = 256;
constexpr int HWc = 48 * 48;           // 2304
constexpr float BN_EPS = 1e-5f;

typedef unsigned short u16;
typedef __attribute__((ext_vector_type(8))) short short8;   // 8 bf16 (4 VGPRs)
typedef __attribute__((ext_vector_type(4))) float f32x4;    // MFMA C/D frag

__device__ __forceinline__ u16 f2bf(float f) {
    uint32_t u = __builtin_bit_cast(uint32_t, f);
    u += 0x7fffu + ((u >> 16) & 1u);     // RNE
    return (u16)(u >> 16);
}
__device__ __forceinline__ float bf2f(u16 h) {
    uint32_t u = ((uint32_t)h) << 16;
    return __builtin_bit_cast(float, u);
}
// async global->LDS, 16B per lane; lds dst is wave-uniform base (HW adds lane*16)
__device__ __forceinline__ void load_lds16(const void* g, void* l) {
    __builtin_amdgcn_global_load_lds(
        (const __attribute__((address_space(1))) void*)(uintptr_t)g,
        (__attribute__((address_space(3))) void*)(uintptr_t)l, 16, 0, 0);
}
template <int N> __device__ __forceinline__ void wait_vmcnt() {
    if constexpr (N == 0)       asm volatile("s_waitcnt vmcnt(0)" ::: "memory");
    else if constexpr (N == 3)  asm volatile("s_waitcnt vmcnt(3)" ::: "memory");
    else if constexpr (N == 4)  asm volatile("s_waitcnt vmcnt(4)" ::: "memory");
    else if constexpr (N == 6)  asm volatile("s_waitcnt vmcnt(6)" ::: "memory");
    else if constexpr (N == 8)  asm volatile("s_waitcnt vmcnt(8)" ::: "memory");
    else if constexpr (N == 9)  asm volatile("s_waitcnt vmcnt(9)" ::: "memory");
    else if constexpr (N == 12) asm volatile("s_waitcnt vmcnt(12)" ::: "memory");
}
__device__ __forceinline__ void wait_lgkm0() {
    asm volatile("s_waitcnt lgkmcnt(0)" ::: "memory");
}
__device__ __forceinline__ void barrier_fenced() {
    __builtin_amdgcn_s_barrier();
    asm volatile("" ::: "memory");      // keep LDS reads below the barrier
}

// ---------------------------------------------------------------------------
// Front cast: thph_w bf16 (rows 0..255=th_w, 256..511=ph_w), g_w bf16,
// bias_thph fp32 [th_b | ph_b].
// ---------------------------------------------------------------------------
__global__ __launch_bounds__(256)
void cast_front(const float* __restrict__ th_w, const float* __restrict__ ph_w,
                const float* __restrict__ g_w, const float* __restrict__ th_b,
                const float* __restrict__ ph_b, u16* __restrict__ wcat,
                float* __restrict__ bias_thph) {
    int idx = blockIdx.x * 256 + threadIdx.x;
    if (idx < 98304) {                           // ushort4 casts
        const float4* src;
        if (idx < 32768)       src = (const float4*)th_w + idx;
        else if (idx < 65536)  src = (const float4*)ph_w + (idx - 32768);
        else                   src = (const float4*)g_w  + (idx - 65536);
        float4 v = *src;
        ushort4 o;
        o.x = f2bf(v.x); o.y = f2bf(v.y); o.z = f2bf(v.z); o.w = f2bf(v.w);
        ((ushort4*)wcat)[idx] = o;
    } else if (idx < 98816) {                    // 512 bias floats
        int i = idx - 98304;
        bias_thph[i] = (i < 256) ? th_b[i] : ph_b[i - 256];
    }
}

__global__ __launch_bounds__(256)
void cast_w(const float* __restrict__ a, u16* __restrict__ out) {
    int idx = blockIdx.x * 256 + threadIdx.x;    // 0..32767
    float4 v = ((const float4*)a)[idx];
    ushort4 o;
    o.x = f2bf(v.x); o.y = f2bf(v.y); o.z = f2bf(v.z); o.w = f2bf(v.w);
    ((ushort4*)out)[idx] = o;
}

// ---------------------------------------------------------------------------
// x (B,C,HW) fp32 -> xt (B,HW,C) bf16, 64c x 32p LDS-tiled, ushort2 stores
// ---------------------------------------------------------------------------
__global__ __launch_bounds__(256)
void transpose_cast_x(const float* __restrict__ x, u16* __restrict__ xt) {
    __shared__ float t[64][33];
    const int b = blockIdx.z;
    const int p0 = blockIdx.x * 32;     // HW dir
    const int c0 = blockIdx.y * 64;     // C dir
    const int tx = threadIdx.x & 31, ty = threadIdx.x >> 5;   // ty 0..7
    const float* xb = x + (size_t)b * Cc * HWc;
#pragma unroll
    for (int r = 0; r < 8; ++r)
        t[r * 8 + ty][tx] = xb[(size_t)(c0 + r * 8 + ty) * HWc + p0 + tx];
    __syncthreads();
    u16* xtb = xt + (size_t)b * HWc * Cc;
    const int cc = (threadIdx.x & 31) * 2, pp = threadIdx.x >> 5;
#pragma unroll
    for (int r = 0; r < 4; ++r) {
        int p = r * 8 + pp;
        ushort2 v;
        v.x = f2bf(t[cc][p]);
        v.y = f2bf(t[cc + 1][p]);
        *(ushort2*)&xtb[(size_t)(p0 + p) * Cc + c0 + cc] = v;
    }
}

// ---------------------------------------------------------------------------
// bf16 MFMA GEMM: C[m][n] = sum_k A[m][k] * B[n][k] (+ bias)
//   A: (M,K) bf16, B: (N,K) bf16, both K-contiguous.
//   TM=128: 128x128 tile, wave layout 2x2 (64x64 each).
//   TM=64 :  64x128 tile, wave layout 2x2 (32x64 each).
//
// 4-buffer pipeline, prefetch depth 3, counted vmcnt (T3/T4). Each iter
// issues stage(t+3); `s_waitcnt vmcnt(3*LPS)` waits only for stage(t), so
// loads get THREE compute phases (~900cy) to land — covering L3/HBM latency
// that depth-2 (round 2: ~600cy cover, PV iter ~1500cy with a ~300-900cy
// residual stall at the wait) did not. Raw s_barrier + asm waits; lgkmcnt(0)
// before the tail barrier so no wave leaves the compute phase with LDS reads
// outstanding (buffer is re-staged next iteration).
//
// LDS XOR swizzle (T2, rule 21: linear dest + inverse-swizzled SOURCE +
// swizzled READ): 16B chunk q of row r lives at slot q ^ ((r>>1)&3). Spreads
// the 16 m16-lanes of a quarter-wave over all 8 (bank-group x parity)
// positions -> 2-way (free) instead of 8-way. Verified round 1-2:
// SQ_LDS_BANK_CONFLICT 3.98M -> 0.
//
// STORE==0: bf16 C; STORE==1: fp32 C. STATS: fused per-channel(m) sum/sumsq
// via 16-lane shuffle reduce + atomicAdd. bias_mode: 0 none, 1 per-n, 2 per-m.
// ---------------------------------------------------------------------------
template <int TM, int STORE, bool STATS>
__global__ __launch_bounds__(256, 2)
void mfma_gemm(const u16* __restrict__ A, const u16* __restrict__ B,
               void* __restrict__ Cout, const float* __restrict__ bias,
               int bias_mode, int K, int ldA, int ldB, int ldC,
               size_t sA, size_t sB, size_t sC,
               float* __restrict__ s0g, float* __restrict__ s1g) {
    constexpr int MI  = TM / 32;                 // 4 (TM=128) or 2 (TM=64)
    constexpr int LPS = (TM == 128) ? 4 : 3;     // global_load_lds per wave/stage
    __shared__ __align__(16) u16 As[4][TM * 32];
    __shared__ __align__(16) u16 Bs[4][128 * 32];
    const int bz = blockIdx.z;
    const int m0 = blockIdx.y * TM, n0 = blockIdx.x * 128;
    const u16* Ab = A + (size_t)bz * sA + (size_t)m0 * ldA;
    const u16* Bb = B + (size_t)bz * sB + (size_t)n0 * ldB;
    const int tid = threadIdx.x, lane = tid & 63, w = tid >> 6;
    const int wm = (w & 1) * (TM / 2);
    const int wn = (w >> 1) * 64;
    const int quad = lane >> 4, m16 = lane & 15;

    f32x4 acc[MI][4];
#pragma unroll
    for (int i = 0; i < MI; ++i)
#pragma unroll
        for (int j = 0; j < 4; ++j) acc[i][j] = (f32x4){0.f, 0.f, 0.f, 0.f};

    // staging: linear slot L -> row = L>>2; SOURCE chunk = (L&3)^((L>>3)&3)
    // (inverse of the read swizzle; both are the same involution)
    const int L0 = 2 * w * 64 + lane, L1 = L0 + 64;
    const int br0 = L0 >> 2, bc0 = ((L0 & 3) ^ ((L0 >> 3) & 3)) * 8;
    const int br1 = L1 >> 2, bc1 = ((L1 & 3) ^ ((L1 >> 3) & 3)) * 8;
    const int ar0 = (TM == 128) ? br0 : (tid >> 2);
    const int ac0 = (TM == 128) ? bc0 : (((tid & 3) ^ ((tid >> 3) & 3)) * 8);

    auto stage = [&](int buf, int k0) {
        if (TM == 128) {
            load_lds16(Ab + (size_t)ar0 * ldA + k0 + ac0, &As[buf][2 * w * 512]);
            load_lds16(Ab + (size_t)br1 * ldA + k0 + bc1, &As[buf][(2 * w + 1) * 512]);
        } else {
            load_lds16(Ab + (size_t)ar0 * ldA + k0 + ac0, &As[buf][w * 512]);
        }
        load_lds16(Bb + (size_t)br0 * ldB + k0 + bc0, &Bs[buf][2 * w * 512]);
        load_lds16(Bb + (size_t)br1 * ldB + k0 + bc1, &Bs[buf][(2 * w + 1) * 512]);
    };

    // swizzled read: chunk quad of row r is at slot quad ^ ((r>>1)&3);
    // (r>>1)&3 == (m16>>1)&3 for every row this lane touches.
    const int sq = (quad ^ ((m16 >> 1) & 3)) * 8;

    auto compute = [&](int buf) {
        short8 af[MI], bfv[4];
#pragma unroll
        for (int i = 0; i < MI; ++i)
            af[i] = *(const short8*)&As[buf][(wm + i * 16 + m16) * 32 + sq];
#pragma unroll
        for (int j = 0; j < 4; ++j)
            bfv[j] = *(const short8*)&Bs[buf][(wn + j * 16 + m16) * 32 + sq];
#pragma unroll
        for (int i = 0; i < MI; ++i)
#pragma unroll
            for (int j = 0; j < 4; ++j)
                acc[i][j] = __builtin_amdgcn_mfma_f32_16x16x32_bf16(
                    af[i], bfv[j], acc[i][j], 0, 0, 0);
    };

    const int nt = K / 32;                       // >= 8 for all our shapes
    // prologue: fill buffers 0,1,2 (3*LPS loads in flight)
    stage(0, 0);
    stage(1, 32);
    stage(2, 64);

    int cur = 0;
    for (int t = 0; t < nt - 3; ++t) {
        int nxt = cur + 3; if (nxt >= 4) nxt -= 4;
        stage(nxt, (t + 3) * 32);                // buf consumed at t-1; safe
        wait_vmcnt<3 * LPS>();                   // stage(t) landed; t+1..t+3 fly
        barrier_fenced();                        // ...for ALL waves
        compute(cur);
        wait_lgkm0();                            // our LDS reads done
        barrier_fenced();                        // all waves done with buf[cur]
        ++cur; cur &= 3;
    }
    // t = nt-3: stages nt-3, nt-2, nt-1 outstanding
    wait_vmcnt<2 * LPS>();
    barrier_fenced();
    compute(cur);
    wait_lgkm0();
    barrier_fenced();
    ++cur; cur &= 3;
    // t = nt-2: stages nt-2, nt-1 outstanding
    wait_vmcnt<LPS>();
    barrier_fenced();
    compute(cur);
    wait_lgkm0();
    barrier_fenced();
    ++cur; cur &= 3;
    // t = nt-1: last stage outstanding
    wait_vmcnt<0>();
    barrier_fenced();
    compute(cur);

    // bias into acc (C/D layout m89: col n = lane&15, row m = quad*4 + reg)
    if (bias_mode) {
#pragma unroll
        for (int i = 0; i < MI; ++i)
#pragma unroll
            for (int j = 0; j < 4; ++j)
#pragma unroll
                for (int r = 0; r < 4; ++r)
                    acc[i][j][r] += (bias_mode == 2)
                        ? bias[m0 + wm + i * 16 + quad * 4 + r]
                        : bias[n0 + wn + j * 16 + m16];
    }

    if (STORE == 0) {
        u16* C = (u16*)Cout + (size_t)bz * sC;
#pragma unroll
        for (int i = 0; i < MI; ++i) {
            int m = m0 + wm + i * 16 + quad * 4;
#pragma unroll
            for (int j = 0; j < 4; ++j) {
                int n = n0 + wn + j * 16 + m16;
#pragma unroll
                for (int r = 0; r < 4; ++r)
                    C[(size_t)(m + r) * ldC + n] = f2bf(acc[i][j][r]);
            }
        }
    } else {
        float* C = (float*)Cout + (size_t)bz * sC;
#pragma unroll
        for (int i = 0; i < MI; ++i) {
            int m = m0 + wm + i * 16 + quad * 4;
#pragma unroll
            for (int j = 0; j < 4; ++j) {
                int n = n0 + wn + j * 16 + m16;
#pragma unroll
                for (int r = 0; r < 4; ++r)
                    C[(size_t)(m + r) * ldC + n] = acc[i][j][r];
            }
        }
    }

    if (STATS) {
        // per-row partial sums over this wave's 64 n-cols, then atomic
#pragma unroll
        for (int i = 0; i < MI; ++i) {
#pragma unroll
            for (int r = 0; r < 4; ++r) {
                float v0 = 0.f, v1 = 0.f;
#pragma unroll
                for (int j = 0; j < 4; ++j) {
                    float v = acc[i][j][r];
                    v0 += v;
                    v1 = fmaf(v, v, v1);
                }
#pragma unroll
                for (int off = 8; off; off >>= 1) {
                    v0 += __shfl_down(v0, off, 16);
                    v1 += __shfl_down(v1, off, 16);
                }
                if (m16 == 0) {
                    int m = m0 + wm + i * 16 + quad * 4 + r;
                    atomicAdd(&s0g[m], v0);
                    atomicAdd(&s1g[m], v1);
                }
            }
        }
    }
}

// ---------------------------------------------------------------------------
// In-place row softmax on bf16 S (rows of 2304). 192 threads, 12 elems each.
// ---------------------------------------------------------------------------
__global__ __launch_bounds__(192)
void softmax_rows(u16* __restrict__ S) {
    const int b = blockIdx.x & 7;
    const int q = blockIdx.x >> 3;
    u16* row = S + ((size_t)b * HWc + q) * (size_t)HWc;
    const int tid = threadIdx.x;

    float v[12];
#pragma unroll
    for (int c = 0; c < 3; ++c) {
        uint2 raw = *(const uint2*)&row[(c * 192 + tid) * 4];
        v[c * 4 + 0] = bf2f((u16)(raw.x & 0xffff));
        v[c * 4 + 1] = bf2f((u16)(raw.x >> 16));
        v[c * 4 + 2] = bf2f((u16)(raw.y & 0xffff));
        v[c * 4 + 3] = bf2f((u16)(raw.y >> 16));
    }
    float m = v[0];
#pragma unroll
    for (int i = 1; i < 12; ++i) m = fmaxf(m, v[i]);
#pragma unroll
    for (int off = 32; off; off >>= 1) m = fmaxf(m, __shfl_down(m, off, 64));
    __shared__ float redm[3], reds[3];
    if ((tid & 63) == 0) redm[tid >> 6] = m;
    __syncthreads();
    m = fmaxf(fmaxf(redm[0], redm[1]), redm[2]);

    float s = 0.f;
#pragma unroll
    for (int i = 0; i < 12; ++i) { v[i] = __expf(v[i] - m); s += v[i]; }
#pragma unroll
    for (int off = 32; off; off >>= 1) s += __shfl_down(s, off, 64);
    if ((tid & 63) == 0) reds[tid >> 6] = s;
    __syncthreads();
    const float rinv = 1.0f / (reds[0] + reds[1] + reds[2]);

#pragma unroll
    for (int c = 0; c < 3; ++c) {
        uint2 o;
        o.x = (uint32_t)f2bf(v[c * 4 + 0] * rinv) |
              ((uint32_t)f2bf(v[c * 4 + 1] * rinv) << 16);
        o.y = (uint32_t)f2bf(v[c * 4 + 2] * rinv) |
              ((uint32_t)f2bf(v[c * 4 + 3] * rinv) << 16);
        *(uint2*)&row[(c * 192 + tid) * 4] = o;
    }
}

// ---------------------------------------------------------------------------
// Normalize (from raw sums) + affine + residual, float4 vectorized
// ---------------------------------------------------------------------------
__global__ __launch_bounds__(256)
void bn_apply(const float* __restrict__ wy, const float* __restrict__ x,
              const float* __restrict__ s0, const float* __restrict__ s1,
              const float* __restrict__ gamma, const float* __restrict__ beta,
              float* __restrict__ out) {
    const size_t i4 = (size_t)blockIdx.x * 256 + threadIdx.x;
    const size_t base = i4 * 4;
    const int o = (int)((base / HWc) % Cc);
    const float N = (float)(Bn * HWc);
    const float mean = s0[o] / N;
    const float var  = s1[o] / N - mean * mean;
    const float rstd = rsqrtf(var + BN_EPS);
    const float ga = gamma[o];
    const float be = beta[o];
    const float4 w4 = ((const float4*)wy)[i4];
    const float4 x4 = ((const float4*)x)[i4];
    float4 r;
    r.x = (w4.x - mean) * rstd * ga + be + x4.x;
    r.y = (w4.y - mean) * rstd * ga + be + x4.y;
    r.z = (w4.z - mean) * rstd * ga + be + x4.z;
    r.w = (w4.w - mean) * rstd * ga + be + x4.w;
    ((float4*)out)[i4] = r;
}

// ---------------------------------------------------------------------------
extern "C" void kernel_launch(void* const* d_in, const int* in_sizes, int n_in,
                              void* d_out, int out_size, void* d_ws, size_t ws_size,
                              hipStream_t stream) {
    const float* x     = (const float*)d_in[0];
    const float* g_w   = (const float*)d_in[1];
    const float* g_b   = (const float*)d_in[2];
    const float* th_w  = (const float*)d_in[3];
    const float* th_b  = (const float*)d_in[4];
    const float* ph_w  = (const float*)d_in[5];
    const float* ph_b  = (const float*)d_in[6];
    const float* w_w   = (const float*)d_in[7];
    const float* w_b   = (const float*)d_in[8];
    const float* gamma = (const float*)d_in[9];
    const float* beta  = (const float*)d_in[10];

    // Workspace aliasing (113.25 MB total, same bound as previous rounds):
    //  [0, 18.87M)      thph bf16 (B,HW,512)  -> later y bf16 (B,HW,IC) at [0,9.44M)
    //                   and post-S: wbf2 + stats at [9.44M, ...)
    //  [18.87M, 28.31M) g bf16 (B,IC,HW)
    //  [28.31M, 113.25M) Sreg: pre-S hosts xt bf16 (B,HW,C) + wcat + bias_thph;
    //                   S bf16 (B,HW,HW); post-PV wy fp32 (B,C,HW)
    char* base = (char*)d_ws;
    const size_t SZT = (size_t)Bn * HWc * ICc * 2;        // 9,437,184
    u16* thph = (u16*)base;                               // 18.87 MB
    u16* g    = (u16*)(base + 2 * SZT);                   // 9.44 MB
    char* Sreg = base + 3 * SZT;
    u16* S    = (u16*)Sreg;                               // 84.93 MB
    u16* xt   = (u16*)Sreg;                               // 18.87 MB (pre-S)
    u16* wcat = (u16*)(Sreg + (size_t)Bn * HWc * Cc * 2); // 786 KB (pre-S)
    float* bias_thph = (float*)(Sreg + (size_t)Bn * HWc * Cc * 2 + 786432);
    u16* y    = (u16*)base;                               // 9.44 MB (post-S)
    u16* wbf2 = (u16*)(base + SZT);                       // 262 KB (post-S)
    float* stats = (float*)(base + SZT + 262144);         // 4 KB (post-S)
    float* wy = (float*)Sreg;                             // 37.75 MB (post-PV)

    dim3 blk(256);
    const u16* thphw = wcat;                   // (512,512)
    const u16* gwb   = wcat + 262144;          // (256,512)

    cast_front<<<dim3(386), blk, 0, stream>>>(th_w, ph_w, g_w, th_b, ph_b,
                                              wcat, bias_thph);
    transpose_cast_x<<<dim3(HWc / 32, Cc / 64, Bn), blk, 0, stream>>>(x, xt);

    // thph[q][o] = sum_c xt[q][c]*thph_w[o][c] + bias  (M=2304,N=512,K=512)
    mfma_gemm<128, 0, false><<<dim3(4, 18, Bn), blk, 0, stream>>>(
        xt, thphw, thph, bias_thph, 1, Cc, Cc, Cc, 512,
        (size_t)HWc * Cc, 0, (size_t)HWc * 512, nullptr, nullptr);

    // g[ic][p] = sum_c g_w[ic][c]*xt[p][c] + g_b[ic]   (M=256,N=2304,K=512)
    mfma_gemm<64, 0, false><<<dim3(18, 4, Bn), blk, 0, stream>>>(
        gwb, xt, g, g_b, 2, Cc, Cc, Cc, HWc,
        0, (size_t)HWc * Cc, (size_t)ICc * HWc, nullptr, nullptr);

    // S = tht . pht^T   (M=N=2304, K=256); tht = thph cols 0..255, pht = +256
    mfma_gemm<128, 0, false><<<dim3(18, 18, Bn), blk, 0, stream>>>(
        thph, thph + 256, S, nullptr, 0, ICc, 512, 512, HWc,
        (size_t)HWc * 512, (size_t)HWc * 512, (size_t)HWc * HWc,
        nullptr, nullptr);

    // w_w -> bf16 and zero stats (into regions dead after S-gemm)
    cast_w<<<dim3(128), blk, 0, stream>>>(w_w, wbf2);
    hipMemsetAsync(stats, 0, 2 * Cc * sizeof(float), stream);

    // softmax rows, in place
    softmax_rows<<<dim3(Bn * HWc), dim3(192), 0, stream>>>(S);

    // y[q][ic] = sum_k P[q][k]*g[ic][k]  (M=2304,N=256,K=2304), TM=64: 576 blk
    mfma_gemm<64, 0, false><<<dim3(2, 36, Bn), blk, 0, stream>>>(
        S, g, y, nullptr, 0, HWc, HWc, HWc, ICc,
        (size_t)HWc * HWc, (size_t)ICc * HWc, (size_t)HWc * ICc,
        nullptr, nullptr);

    // wy[o][p] = sum_ic w_w[o][ic]*y[p][ic] + w_b[o]  (M=512,N=2304,K=256)
    // fp32 out + fused BN sum/sumsq
    mfma_gemm<128, 1, true><<<dim3(18, 4, Bn), blk, 0, stream>>>(
        wbf2, y, wy, w_b, 2, ICc, ICc, ICc, HWc,
        0, (size_t)HWc * ICc, (size_t)Cc * HWc, stats, stats + Cc);

    // BatchNorm apply (stats from raw sums) + affine + residual
    bn_apply<<<dim3((Bn * Cc * HWc) / 4 / 256), blk, 0, stream>>>(
        wy, x, stats, stats + Cc, gamma, beta, (float*)d_out);
}

// Round 9
// 320.550 us; speedup vs baseline: 1.4140x; 1.0063x over previous
//
#include <hip/hip_runtime.h>
#include <hip/hip_bf16.h>
#include <stdint.h>

// Problem constants (fixed by setup_inputs)
constexpr int Bn  = 8;
constexpr int Cc  = 512;
constexpr int ICc = 256;
constexpr int HWc = 48 * 48;           // 2304
constexpr float BN_EPS = 1e-5f;

typedef unsigned short u16;
typedef __attribute__((ext_vector_type(8))) short short8;   // 8 bf16 (4 VGPRs)
typedef __attribute__((ext_vector_type(4))) float f32x4;    // MFMA C/D frag

__device__ __forceinline__ u16 f2bf(float f) {
    uint32_t u = __builtin_bit_cast(uint32_t, f);
    u += 0x7fffu + ((u >> 16) & 1u);     // RNE
    return (u16)(u >> 16);
}
__device__ __forceinline__ float bf2f(u16 h) {
    uint32_t u = ((uint32_t)h) << 16;
    return __builtin_bit_cast(float, u);
}
// async global->LDS, 16B per lane; lds dst is wave-uniform base (HW adds lane*16)
__device__ __forceinline__ void load_lds16(const void* g, void* l) {
    __builtin_amdgcn_global_load_lds(
        (const __attribute__((address_space(1))) void*)(uintptr_t)g,
        (__attribute__((address_space(3))) void*)(uintptr_t)l, 16, 0, 0);
}
template <int N> __device__ __forceinline__ void wait_vmcnt() {
    if constexpr (N == 0)       asm volatile("s_waitcnt vmcnt(0)" ::: "memory");
    else if constexpr (N == 3)  asm volatile("s_waitcnt vmcnt(3)" ::: "memory");
    else if constexpr (N == 4)  asm volatile("s_waitcnt vmcnt(4)" ::: "memory");
    else if constexpr (N == 6)  asm volatile("s_waitcnt vmcnt(6)" ::: "memory");
    else if constexpr (N == 8)  asm volatile("s_waitcnt vmcnt(8)" ::: "memory");
    else if constexpr (N == 9)  asm volatile("s_waitcnt vmcnt(9)" ::: "memory");
    else if constexpr (N == 12) asm volatile("s_waitcnt vmcnt(12)" ::: "memory");
}
__device__ __forceinline__ void wait_lgkm0() {
    asm volatile("s_waitcnt lgkmcnt(0)" ::: "memory");
}
__device__ __forceinline__ void barrier_fenced() {
    __builtin_amdgcn_s_barrier();
    asm volatile("" ::: "memory");      // keep LDS reads below the barrier
}

// ---------------------------------------------------------------------------
// Front cast: thph_w bf16 (rows 0..255=th_w, 256..511=ph_w), g_w bf16,
// bias_thph fp32 [th_b | ph_b].
// ---------------------------------------------------------------------------
__global__ __launch_bounds__(256)
void cast_front(const float* __restrict__ th_w, const float* __restrict__ ph_w,
                const float* __restrict__ g_w, const float* __restrict__ th_b,
                const float* __restrict__ ph_b, u16* __restrict__ wcat,
                float* __restrict__ bias_thph) {
    int idx = blockIdx.x * 256 + threadIdx.x;
    if (idx < 98304) {                           // ushort4 casts
        const float4* src;
        if (idx < 32768)       src = (const float4*)th_w + idx;
        else if (idx < 65536)  src = (const float4*)ph_w + (idx - 32768);
        else                   src = (const float4*)g_w  + (idx - 65536);
        float4 v = *src;
        ushort4 o;
        o.x = f2bf(v.x); o.y = f2bf(v.y); o.z = f2bf(v.z); o.w = f2bf(v.w);
        ((ushort4*)wcat)[idx] = o;
    } else if (idx < 98816) {                    // 512 bias floats
        int i = idx - 98304;
        bias_thph[i] = (i < 256) ? th_b[i] : ph_b[i - 256];
    }
}

__global__ __launch_bounds__(256)
void cast_w(const float* __restrict__ a, u16* __restrict__ out) {
    int idx = blockIdx.x * 256 + threadIdx.x;    // 0..32767
    float4 v = ((const float4*)a)[idx];
    ushort4 o;
    o.x = f2bf(v.x); o.y = f2bf(v.y); o.z = f2bf(v.z); o.w = f2bf(v.w);
    ((ushort4*)out)[idx] = o;
}

// ---------------------------------------------------------------------------
// x (B,C,HW) fp32 -> xt (B,HW,C) bf16, 64c x 32p LDS-tiled, ushort2 stores
// ---------------------------------------------------------------------------
__global__ __launch_bounds__(256)
void transpose_cast_x(const float* __restrict__ x, u16* __restrict__ xt) {
    __shared__ float t[64][33];
    const int b = blockIdx.z;
    const int p0 = blockIdx.x * 32;     // HW dir
    const int c0 = blockIdx.y * 64;     // C dir
    const int tx = threadIdx.x & 31, ty = threadIdx.x >> 5;   // ty 0..7
    const float* xb = x + (size_t)b * Cc * HWc;
#pragma unroll
    for (int r = 0; r < 8; ++r)
        t[r * 8 + ty][tx] = xb[(size_t)(c0 + r * 8 + ty) * HWc + p0 + tx];
    __syncthreads();
    u16* xtb = xt + (size_t)b * HWc * Cc;
    const int cc = (threadIdx.x & 31) * 2, pp = threadIdx.x >> 5;
#pragma unroll
    for (int r = 0; r < 4; ++r) {
        int p = r * 8 + pp;
        ushort2 v;
        v.x = f2bf(t[cc][p]);
        v.y = f2bf(t[cc + 1][p]);
        *(ushort2*)&xtb[(size_t)(p0 + p) * Cc + c0 + cc] = v;
    }
}

// ---------------------------------------------------------------------------
// bf16 MFMA GEMM: C[m][n] = sum_k A[m][k] * B[n][k] (+ bias)
//   A: (M,K) bf16, B: (N,K) bf16, both K-contiguous.
//   TM=128: 128x128 tile, wave layout 2x2 (64x64 each).
//   TM=64 :  64x128 tile, wave layout 2x2 (32x64 each).
//
// Pipelined staging with counted vmcnt (T3/T4). NBUF is chosen per tile so
// LDS stays at 48KB = 3 blocks/CU in BOTH variants (round-7 lesson: 4-buffer
// TM=128 hit 64KB -> 2 blocks/CU -> W-gemm 50->70us; occupancy slot is worth
// more than pipeline depth for these latency-bound shapes):
//   TM=128: NBUF=3 (depth 2): As 24KB + Bs 24KB   [round-2 verified]
//   TM=64 : NBUF=4 (depth 3): As 16KB + Bs 32KB   [round-7 verified, PV gain]
// `s_waitcnt vmcnt(DEPTH*LPS)` waits only for stage(t); stages t+1..t+DEPTH
// stay in flight across the barrier. Raw s_barrier + asm waits; lgkmcnt(0)
// before the tail barrier so no wave leaves compute with LDS reads
// outstanding (buffer is re-staged DEPTH iters later).
//
// LDS XOR swizzle (T2, rule 21: linear dest + inverse-swizzled SOURCE +
// swizzled READ): 16B chunk q of row r lives at slot q ^ ((r>>1)&3) ->
// SQ_LDS_BANK_CONFLICT 3.98M -> 0 (round-1 verified).
//
// STORE==0: bf16 C; STORE==1: fp32 C. STATS: fused per-channel(m) sum/sumsq
// via 16-lane shuffle reduce + atomicAdd. bias_mode: 0 none, 1 per-n, 2 per-m.
// ---------------------------------------------------------------------------
template <int TM, int STORE, bool STATS>
__global__ __launch_bounds__(256, 2)
void mfma_gemm(const u16* __restrict__ A, const u16* __restrict__ B,
               void* __restrict__ Cout, const float* __restrict__ bias,
               int bias_mode, int K, int ldA, int ldB, int ldC,
               size_t sA, size_t sB, size_t sC,
               float* __restrict__ s0g, float* __restrict__ s1g) {
    constexpr int MI    = TM / 32;               // 4 (TM=128) or 2 (TM=64)
    constexpr int LPS   = (TM == 128) ? 4 : 3;   // global_load_lds per wave/stage
    constexpr int NBUF  = (TM == 128) ? 3 : 4;   // keeps LDS at 48KB either way
    constexpr int DEPTH = NBUF - 1;
    __shared__ __align__(16) u16 As[NBUF][TM * 32];
    __shared__ __align__(16) u16 Bs[NBUF][128 * 32];
    const int bz = blockIdx.z;
    const int m0 = blockIdx.y * TM, n0 = blockIdx.x * 128;
    const u16* Ab = A + (size_t)bz * sA + (size_t)m0 * ldA;
    const u16* Bb = B + (size_t)bz * sB + (size_t)n0 * ldB;
    const int tid = threadIdx.x, lane = tid & 63, w = tid >> 6;
    const int wm = (w & 1) * (TM / 2);
    const int wn = (w >> 1) * 64;
    const int quad = lane >> 4, m16 = lane & 15;

    f32x4 acc[MI][4];
#pragma unroll
    for (int i = 0; i < MI; ++i)
#pragma unroll
        for (int j = 0; j < 4; ++j) acc[i][j] = (f32x4){0.f, 0.f, 0.f, 0.f};

    // staging: linear slot L -> row = L>>2; SOURCE chunk = (L&3)^((L>>3)&3)
    // (inverse of the read swizzle; both are the same involution)
    const int L0 = 2 * w * 64 + lane, L1 = L0 + 64;
    const int br0 = L0 >> 2, bc0 = ((L0 & 3) ^ ((L0 >> 3) & 3)) * 8;
    const int br1 = L1 >> 2, bc1 = ((L1 & 3) ^ ((L1 >> 3) & 3)) * 8;
    const int ar0 = (TM == 128) ? br0 : (tid >> 2);
    const int ac0 = (TM == 128) ? bc0 : (((tid & 3) ^ ((tid >> 3) & 3)) * 8);

    auto stage = [&](int buf, int k0) {
        if (TM == 128) {
            load_lds16(Ab + (size_t)ar0 * ldA + k0 + ac0, &As[buf][2 * w * 512]);
            load_lds16(Ab + (size_t)br1 * ldA + k0 + bc1, &As[buf][(2 * w + 1) * 512]);
        } else {
            load_lds16(Ab + (size_t)ar0 * ldA + k0 + ac0, &As[buf][w * 512]);
        }
        load_lds16(Bb + (size_t)br0 * ldB + k0 + bc0, &Bs[buf][2 * w * 512]);
        load_lds16(Bb + (size_t)br1 * ldB + k0 + bc1, &Bs[buf][(2 * w + 1) * 512]);
    };

    // swizzled read: chunk quad of row r is at slot quad ^ ((r>>1)&3);
    // (r>>1)&3 == (m16>>1)&3 for every row this lane touches.
    const int sq = (quad ^ ((m16 >> 1) & 3)) * 8;

    auto compute = [&](int buf) {
        short8 af[MI], bfv[4];
#pragma unroll
        for (int i = 0; i < MI; ++i)
            af[i] = *(const short8*)&As[buf][(wm + i * 16 + m16) * 32 + sq];
#pragma unroll
        for (int j = 0; j < 4; ++j)
            bfv[j] = *(const short8*)&Bs[buf][(wn + j * 16 + m16) * 32 + sq];
#pragma unroll
        for (int i = 0; i < MI; ++i)
#pragma unroll
            for (int j = 0; j < 4; ++j)
                acc[i][j] = __builtin_amdgcn_mfma_f32_16x16x32_bf16(
                    af[i], bfv[j], acc[i][j], 0, 0, 0);
    };

    const int nt = K / 32;                       // >= 8 for all our shapes
    // prologue: fill DEPTH buffers (DEPTH*LPS loads in flight)
#pragma unroll
    for (int p = 0; p < DEPTH; ++p) stage(p, p * 32);

    int cur = 0;
    for (int t = 0; t < nt - DEPTH; ++t) {
        int nxt = cur + DEPTH; if (nxt >= NBUF) nxt -= NBUF;
        stage(nxt, (t + DEPTH) * 32);            // buf consumed at t-1; safe
        wait_vmcnt<DEPTH * LPS>();               // stage(t) landed; rest fly
        barrier_fenced();                        // ...for ALL waves
        compute(cur);
        wait_lgkm0();                            // our LDS reads done
        barrier_fenced();                        // all waves done with buf[cur]
        ++cur; if (cur == NBUF) cur = 0;
    }
    // epilogue: DEPTH stages outstanding, drain one per step
    if constexpr (DEPTH == 3) {
        wait_vmcnt<2 * LPS>();
        barrier_fenced();
        compute(cur);
        wait_lgkm0();
        barrier_fenced();
        ++cur; if (cur == NBUF) cur = 0;
    }
    wait_vmcnt<LPS>();
    barrier_fenced();
    compute(cur);
    wait_lgkm0();
    barrier_fenced();
    ++cur; if (cur == NBUF) cur = 0;
    wait_vmcnt<0>();
    barrier_fenced();
    compute(cur);

    // bias into acc (C/D layout m89: col n = lane&15, row m = quad*4 + reg)
    if (bias_mode) {
#pragma unroll
        for (int i = 0; i < MI; ++i)
#pragma unroll
            for (int j = 0; j < 4; ++j)
#pragma unroll
                for (int r = 0; r < 4; ++r)
                    acc[i][j][r] += (bias_mode == 2)
                        ? bias[m0 + wm + i * 16 + quad * 4 + r]
                        : bias[n0 + wn + j * 16 + m16];
    }

    if (STORE == 0) {
        u16* C = (u16*)Cout + (size_t)bz * sC;
#pragma unroll
        for (int i = 0; i < MI; ++i) {
            int m = m0 + wm + i * 16 + quad * 4;
#pragma unroll
            for (int j = 0; j < 4; ++j) {
                int n = n0 + wn + j * 16 + m16;
#pragma unroll
                for (int r = 0; r < 4; ++r)
                    C[(size_t)(m + r) * ldC + n] = f2bf(acc[i][j][r]);
            }
        }
    } else {
        float* C = (float*)Cout + (size_t)bz * sC;
#pragma unroll
        for (int i = 0; i < MI; ++i) {
            int m = m0 + wm + i * 16 + quad * 4;
#pragma unroll
            for (int j = 0; j < 4; ++j) {
                int n = n0 + wn + j * 16 + m16;
#pragma unroll
                for (int r = 0; r < 4; ++r)
                    C[(size_t)(m + r) * ldC + n] = acc[i][j][r];
            }
        }
    }

    if (STATS) {
        // per-row partial sums over this wave's 64 n-cols, then atomic
#pragma unroll
        for (int i = 0; i < MI; ++i) {
#pragma unroll
            for (int r = 0; r < 4; ++r) {
                float v0 = 0.f, v1 = 0.f;
#pragma unroll
                for (int j = 0; j < 4; ++j) {
                    float v = acc[i][j][r];
                    v0 += v;
                    v1 = fmaf(v, v, v1);
                }
#pragma unroll
                for (int off = 8; off; off >>= 1) {
                    v0 += __shfl_down(v0, off, 16);
                    v1 += __shfl_down(v1, off, 16);
                }
                if (m16 == 0) {
                    int m = m0 + wm + i * 16 + quad * 4 + r;
                    atomicAdd(&s0g[m], v0);
                    atomicAdd(&s1g[m], v1);
                }
            }
        }
    }
}

// ---------------------------------------------------------------------------
// In-place row softmax on bf16 S (rows of 2304). 192 threads, 12 elems each.
// ---------------------------------------------------------------------------
__global__ __launch_bounds__(192)
void softmax_rows(u16* __restrict__ S) {
    const int b = blockIdx.x & 7;
    const int q = blockIdx.x >> 3;
    u16* row = S + ((size_t)b * HWc + q) * (size_t)HWc;
    const int tid = threadIdx.x;

    float v[12];
#pragma unroll
    for (int c = 0; c < 3; ++c) {
        uint2 raw = *(const uint2*)&row[(c * 192 + tid) * 4];
        v[c * 4 + 0] = bf2f((u16)(raw.x & 0xffff));
        v[c * 4 + 1] = bf2f((u16)(raw.x >> 16));
        v[c * 4 + 2] = bf2f((u16)(raw.y & 0xffff));
        v[c * 4 + 3] = bf2f((u16)(raw.y >> 16));
    }
    float m = v[0];
#pragma unroll
    for (int i = 1; i < 12; ++i) m = fmaxf(m, v[i]);
#pragma unroll
    for (int off = 32; off; off >>= 1) m = fmaxf(m, __shfl_down(m, off, 64));
    __shared__ float redm[3], reds[3];
    if ((tid & 63) == 0) redm[tid >> 6] = m;
    __syncthreads();
    m = fmaxf(fmaxf(redm[0], redm[1]), redm[2]);

    float s = 0.f;
#pragma unroll
    for (int i = 0; i < 12; ++i) { v[i] = __expf(v[i] - m); s += v[i]; }
#pragma unroll
    for (int off = 32; off; off >>= 1) s += __shfl_down(s, off, 64);
    if ((tid & 63) == 0) reds[tid >> 6] = s;
    __syncthreads();
    const float rinv = 1.0f / (reds[0] + reds[1] + reds[2]);

#pragma unroll
    for (int c = 0; c < 3; ++c) {
        uint2 o;
        o.x = (uint32_t)f2bf(v[c * 4 + 0] * rinv) |
              ((uint32_t)f2bf(v[c * 4 + 1] * rinv) << 16);
        o.y = (uint32_t)f2bf(v[c * 4 + 2] * rinv) |
              ((uint32_t)f2bf(v[c * 4 + 3] * rinv) << 16);
        *(uint2*)&row[(c * 192 + tid) * 4] = o;
    }
}

// ---------------------------------------------------------------------------
// Normalize (from raw sums) + affine + residual, float4 vectorized
// ---------------------------------------------------------------------------
__global__ __launch_bounds__(256)
void bn_apply(const float* __restrict__ wy, const float* __restrict__ x,
              const float* __restrict__ s0, const float* __restrict__ s1,
              const float* __restrict__ gamma, const float* __restrict__ beta,
              float* __restrict__ out) {
    const size_t i4 = (size_t)blockIdx.x * 256 + threadIdx.x;
    const size_t base = i4 * 4;
    const int o = (int)((base / HWc) % Cc);
    const float N = (float)(Bn * HWc);
    const float mean = s0[o] / N;
    const float var  = s1[o] / N - mean * mean;
    const float rstd = rsqrtf(var + BN_EPS);
    const float ga = gamma[o];
    const float be = beta[o];
    const float4 w4 = ((const float4*)wy)[i4];
    const float4 x4 = ((const float4*)x)[i4];
    float4 r;
    r.x = (w4.x - mean) * rstd * ga + be + x4.x;
    r.y = (w4.y - mean) * rstd * ga + be + x4.y;
    r.z = (w4.z - mean) * rstd * ga + be + x4.z;
    r.w = (w4.w - mean) * rstd * ga + be + x4.w;
    ((float4*)out)[i4] = r;
}

// ---------------------------------------------------------------------------
extern "C" void kernel_launch(void* const* d_in, const int* in_sizes, int n_in,
                              void* d_out, int out_size, void* d_ws, size_t ws_size,
                              hipStream_t stream) {
    const float* x     = (const float*)d_in[0];
    const float* g_w   = (const float*)d_in[1];
    const float* g_b   = (const float*)d_in[2];
    const float* th_w  = (const float*)d_in[3];
    const float* th_b  = (const float*)d_in[4];
    const float* ph_w  = (const float*)d_in[5];
    const float* ph_b  = (const float*)d_in[6];
    const float* w_w   = (const float*)d_in[7];
    const float* w_b   = (const float*)d_in[8];
    const float* gamma = (const float*)d_in[9];
    const float* beta  = (const float*)d_in[10];

    // Workspace aliasing (113.25 MB total, same bound as previous rounds):
    //  [0, 18.87M)      thph bf16 (B,HW,512)  -> later y bf16 (B,HW,IC) at [0,9.44M)
    //                   and post-S: wbf2 + stats at [9.44M, ...)
    //  [18.87M, 28.31M) g bf16 (B,IC,HW)
    //  [28.31M, 113.25M) Sreg: pre-S hosts xt bf16 (B,HW,C) + wcat + bias_thph;
    //                   S bf16 (B,HW,HW); post-PV wy fp32 (B,C,HW)
    char* base = (char*)d_ws;
    const size_t SZT = (size_t)Bn * HWc * ICc * 2;        // 9,437,184
    u16* thph = (u16*)base;                               // 18.87 MB
    u16* g    = (u16*)(base + 2 * SZT);                   // 9.44 MB
    char* Sreg = base + 3 * SZT;
    u16* S    = (u16*)Sreg;                               // 84.93 MB
    u16* xt   = (u16*)Sreg;                               // 18.87 MB (pre-S)
    u16* wcat = (u16*)(Sreg + (size_t)Bn * HWc * Cc * 2); // 786 KB (pre-S)
    float* bias_thph = (float*)(Sreg + (size_t)Bn * HWc * Cc * 2 + 786432);
    u16* y    = (u16*)base;                               // 9.44 MB (post-S)
    u16* wbf2 = (u16*)(base + SZT);                       // 262 KB (post-S)
    float* stats = (float*)(base + SZT + 262144);         // 4 KB (post-S)
    float* wy = (float*)Sreg;                             // 37.75 MB (post-PV)

    dim3 blk(256);
    const u16* thphw = wcat;                   // (512,512)
    const u16* gwb   = wcat + 262144;          // (256,512)

    cast_front<<<dim3(386), blk, 0, stream>>>(th_w, ph_w, g_w, th_b, ph_b,
                                              wcat, bias_thph);
    transpose_cast_x<<<dim3(HWc / 32, Cc / 64, Bn), blk, 0, stream>>>(x, xt);

    // thph[q][o] = sum_c xt[q][c]*thph_w[o][c] + bias  (M=2304,N=512,K=512)
    mfma_gemm<128, 0, false><<<dim3(4, 18, Bn), blk, 0, stream>>>(
        xt, thphw, thph, bias_thph, 1, Cc, Cc, Cc, 512,
        (size_t)HWc * Cc, 0, (size_t)HWc * 512, nullptr, nullptr);

    // g[ic][p] = sum_c g_w[ic][c]*xt[p][c] + g_b[ic]   (M=256,N=2304,K=512)
    mfma_gemm<64, 0, false><<<dim3(18, 4, Bn), blk, 0, stream>>>(
        gwb, xt, g, g_b, 2, Cc, Cc, Cc, HWc,
        0, (size_t)HWc * Cc, (size_t)ICc * HWc, nullptr, nullptr);

    // S = tht . pht^T   (M=N=2304, K=256); tht = thph cols 0..255, pht = +256
    mfma_gemm<128, 0, false><<<dim3(18, 18, Bn), blk, 0, stream>>>(
        thph, thph + 256, S, nullptr, 0, ICc, 512, 512, HWc,
        (size_t)HWc * 512, (size_t)HWc * 512, (size_t)HWc * HWc,
        nullptr, nullptr);

    // w_w -> bf16 and zero stats (into regions dead after S-gemm)
    cast_w<<<dim3(128), blk, 0, stream>>>(w_w, wbf2);
    hipMemsetAsync(stats, 0, 2 * Cc * sizeof(float), stream);

    // softmax rows, in place
    softmax_rows<<<dim3(Bn * HWc), dim3(192), 0, stream>>>(S);

    // y[q][ic] = sum_k P[q][k]*g[ic][k]  (M=2304,N=256,K=2304), TM=64: 576 blk
    mfma_gemm<64, 0, false><<<dim3(2, 36, Bn), blk, 0, stream>>>(
        S, g, y, nullptr, 0, HWc, HWc, HWc, ICc,
        (size_t)HWc * HWc, (size_t)ICc * HWc, (size_t)HWc * ICc,
        nullptr, nullptr);

    // wy[o][p] = sum_ic w_w[o][ic]*y[p][ic] + w_b[o]  (M=512,N=2304,K=256)
    // fp32 out + fused BN sum/sumsq
    mfma_gemm<128, 1, true><<<dim3(18, 4, Bn), blk, 0, stream>>>(
        wbf2, y, wy, w_b, 2, ICc, ICc, ICc, HWc,
        0, (size_t)HWc * ICc, (size_t)Cc * HWc, stats, stats + Cc);

    // BatchNorm apply (stats from raw sums) + affine + residual
    bn_apply<<<dim3((Bn * Cc * HWc) / 4 / 256), blk, 0, stream>>>(
        wy, x, stats, stats + Cc, gamma, beta, (float*)d_out);
}